// Round 1
// baseline (3328.273 us; speedup 1.0000x reference)
//
#include <hip/hip_runtime.h>
#include <math.h>

// Sizes (fixed by the reference)
#define NB 1024      // batch
#define TT 5         // seq len
#define NN 6         // nodes
#define DD 192       // node feat
#define EE 12        // edge feat
#define MM 12        // message size
#define LL 512       // link hidden
#define OO 6         // out channels
#define BT_TOTAL (NB*TT)   // 5120
#define G 8          // (b,t) pairs per workgroup
#define BLK 384      // 6 waves

__device__ __forceinline__ float sigmoidf_(float x) { return 1.f / (1.f + __expf(-x)); }
__device__ __forceinline__ float dot4(float4 a, float4 b) {
  return a.x*b.x + a.y*b.y + a.z*b.z + a.w*b.w;
}

// One WG handles G consecutive (b,t) pairs end-to-end (both propagate layers),
// all state in LDS; conv1 partial sums are atomically added into out_accum.
__global__ __launch_bounds__(BLK, 3)
void gnn_main(const float* __restrict__ node_resnet,
              const float* __restrict__ pos,
              const int*   __restrict__ attmat,
              const float* __restrict__ link_w1, const float* __restrict__ link_b1,
              const float* __restrict__ link_w2, const float* __restrict__ link_b2,
              const float* __restrict__ msg_Wh,  const float* __restrict__ msg_We,
              const float* __restrict__ msg_b,
              const float* __restrict__ gru_Wih, const float* __restrict__ gru_Whh,
              const float* __restrict__ gru_bih, const float* __restrict__ gru_bhh,
              const float* __restrict__ conv1_w,
              float* __restrict__ out_accum)
{
  __shared__ __align__(16) float sh_h[G][NN][DD+4];   // [p][n][d], padded row
  __shared__ __align__(16) float sh_e[G][36][EE];     // [p][edge(i*6+j)][c]
  __shared__ __align__(16) float sh_m[G][36][MM];
  __shared__ __align__(16) float sh_mh[G][NN][MM];    // [p][j][o], includes msg_b
  __shared__            float sh_adj[G][36];
  __shared__ __align__(16) float sh_msum[G][NN][MM];  // [p][i][o]

  const int tid = threadIdx.x;
  const int p_base = blockIdx.x * G;

  // ---- Phase 0: load h (coalesced) and build edge features ----
  const float* hsrc = node_resnet + (size_t)p_base * (DD*NN);
  for (int i = tid; i < G*DD*NN; i += BLK) {
    int p = i / (DD*NN), rem = i % (DD*NN);
    int d = rem / NN, n = rem % NN;
    sh_h[p][n][d] = hsrc[i];
  }
  for (int idx = tid; idx < G*36*EE; idx += BLK) {
    int p = idx / (36*EE), rem = idx % (36*EE);
    int edge = rem / EE, c = rem % EE;
    int ii = edge / NN, jj = edge % NN;
    int bt = p_base + p;
    int srcn = (c < 6) ? ii : jj;
    int cc   = (c < 6) ? c  : c - 6;
    float v = pos[bt*36 + srcn*6 + cc];
    bool msk = (attmat[bt*36 + edge] == 1) && (ii != jj);
    sh_e[p][edge][c] = msk ? v : 0.f;
  }
  __syncthreads();

  for (int layer = 0; layer < 2; ++layer) {
    // ---- Phase A: adj = sigmoid(link(edge_state)); 1 thread per edge ----
    const float* es_base = (layer == 0) ? &sh_e[0][0][0] : &sh_m[0][0][0];
    if (tid < G*36) {
      int p = tid / 36, edge = tid % 36;
      const float4* ev4 = (const float4*)(es_base + (p*36 + edge)*EE);
      float4 e0 = ev4[0], e1 = ev4[1], e2 = ev4[2];
      const float4* w14 = (const float4*)link_w1;  // wave-uniform -> s_load
      float logit = link_b2[0];
      #pragma unroll 4
      for (int l = 0; l < LL; ++l) {
        float a = link_b1[l]
                + dot4(w14[l*3+0], e0) + dot4(w14[l*3+1], e1) + dot4(w14[l*3+2], e2);
        logit += link_w2[l] * fmaxf(a, 0.f);
      }
      sh_adj[p][edge] = sigmoidf_(logit);
    }
    // ---- Phase B: mh[p][j][o] = msg_b[o] + Wh[o,:]·h[p][j,:]  (disjoint from A) ----
    for (int idx = tid; idx < G*NN*MM; idx += BLK) {
      int p = idx / (NN*MM), rem = idx % (NN*MM);
      int j = rem / MM, o = rem % MM;
      const float4* wrow = (const float4*)(msg_Wh + (size_t)o*DD);
      const float4* hrow = (const float4*)(&sh_h[p][j][0]);
      float acc = msg_b[o];
      #pragma unroll 8
      for (int d4 = 0; d4 < DD/4; ++d4) acc += dot4(wrow[d4], hrow[d4]);
      sh_mh[p][j][o] = acc;
    }
    __syncthreads();

    // ---- Phase C: m = adj * relu(mh_j + We·e) ----
    for (int idx = tid; idx < G*36*MM; idx += BLK) {
      int p = idx / (36*MM), rem = idx % (36*MM);
      int edge = rem / MM, o = rem % MM;
      int jj = edge % NN;
      const float4* we4 = (const float4*)(msg_We + o*EE);
      const float4* ev4 = (const float4*)(&sh_e[p][edge][0]);
      float me = dot4(we4[0], ev4[0]) + dot4(we4[1], ev4[1]) + dot4(we4[2], ev4[2]);
      sh_m[p][edge][o] = sh_adj[p][edge] * fmaxf(sh_mh[p][jj][o] + me, 0.f);
    }
    __syncthreads();

    // ---- Phase D: msum[p][i][o] = sum_j m[p][(i,j)][o] ----
    for (int idx = tid; idx < G*NN*MM; idx += BLK) {
      int p = idx / (NN*MM), rem = idx % (NN*MM);
      int i = rem / MM, o = rem % MM;
      float s = 0.f;
      #pragma unroll
      for (int j = 0; j < NN; ++j) s += sh_m[p][i*NN + j][o];
      sh_msum[p][i][o] = s;
    }
    __syncthreads();

    // ---- Phase E: GRU. thread t owns gate columns {t, t+192, t+384} for 24 rows ----
    {
      const int t  = tid % DD;     // feature/column index 0..191
      const int rg = tid / DD;     // row group 0/1 (rows rg*24 .. +23 of 48)
      float A[24], Bv[24], Cv[24], Dv[24];
      const float bA = gru_bih[t]        + gru_bhh[t];
      const float bB = gru_bih[DD + t]   + gru_bhh[DD + t];
      const float bC = gru_bih[2*DD + t];
      const float bD = gru_bhh[2*DD + t];
      #pragma unroll
      for (int r = 0; r < 24; ++r) { A[r]=bA; Bv[r]=bB; Cv[r]=bC; Dv[r]=bD; }

      // gi = msum @ Wih.T  (rows t, t+192, t+384 of Wih)
      {
        const float4* wi1 = (const float4*)(gru_Wih + (size_t)t*MM);
        const float4* wi2 = (const float4*)(gru_Wih + (size_t)(DD + t)*MM);
        const float4* wi3 = (const float4*)(gru_Wih + (size_t)(2*DD + t)*MM);
        float4 a10=wi1[0], a11=wi1[1], a12=wi1[2];
        float4 a20=wi2[0], a21=wi2[1], a22=wi2[2];
        float4 a30=wi3[0], a31=wi3[1], a32=wi3[2];
        #pragma unroll
        for (int r = 0; r < 24; ++r) {
          int row = rg*24 + r, p = row / NN, n = row % NN;
          const float4* x4 = (const float4*)&sh_msum[p][n][0];
          float4 x0=x4[0], x1=x4[1], x2=x4[2];
          A[r]  += dot4(a10,x0)+dot4(a11,x1)+dot4(a12,x2);
          Bv[r] += dot4(a20,x0)+dot4(a21,x1)+dot4(a22,x2);
          Cv[r] += dot4(a30,x0)+dot4(a31,x1)+dot4(a32,x2);
        }
      }
      // gh = h @ Whh.T (rows t, t+192, t+384 of Whh); h4 reads are wave-uniform -> LDS broadcast
      {
        const float4* w1r = (const float4*)(gru_Whh + (size_t)t*DD);
        const float4* w2r = (const float4*)(gru_Whh + (size_t)(DD + t)*DD);
        const float4* w3r = (const float4*)(gru_Whh + (size_t)(2*DD + t)*DD);
        for (int d4 = 0; d4 < DD/4; ++d4) {
          float4 w1 = w1r[d4], w2 = w2r[d4], w3 = w3r[d4];
          #pragma unroll
          for (int r = 0; r < 24; ++r) {
            int row = rg*24 + r, p = row / NN, n = row % NN;
            float4 hv = *(const float4*)&sh_h[p][n][d4*4];
            A[r] += dot4(w1,hv); Bv[r] += dot4(w2,hv); Dv[r] += dot4(w3,hv);
          }
        }
      }
      __syncthreads();   // all h reads done before in-place update
      #pragma unroll
      for (int r = 0; r < 24; ++r) {
        int row = rg*24 + r, p = row / NN, n = row % NN;
        float hold = sh_h[p][n][t];
        float rr  = sigmoidf_(A[r]);
        float zz  = sigmoidf_(Bv[r]);
        float nn2 = tanhf(Cv[r] + rr*Dv[r]);
        sh_h[p][n][t] = (1.f - zz)*nn2 + zz*hold;
      }
      __syncthreads();
    }
  }

  // ---- Conv1 partials: 48 tasks (p,o), 8 lanes each; atomicAdd into out_accum ----
  {
    int task = tid >> 3, sub = tid & 7;
    int p = task / OO, o = task % OO;
    int bt = p_base + p;
    int b = bt / TT, t = bt % TT;
    float acc = 0.f;
    for (int k = sub; k < NN*DD; k += 8) {
      int n = k / DD, d = k % DD;
      acc += sh_h[p][n][d] * conv1_w[((o*DD + d)*TT + t)*NN + n];
    }
    acc += __shfl_xor(acc, 1);
    acc += __shfl_xor(acc, 2);
    acc += __shfl_xor(acc, 4);
    if (sub == 0) atomicAdd(&out_accum[b*OO + o], acc);
  }
}

// Finalize: out = (relu(acc + conv1_b)) @ conv2_w.T + conv2_b, in place on d_out
__global__ void gnn_final(float* __restrict__ out,
                          const float* __restrict__ conv1_b,
                          const float* __restrict__ conv2_w,
                          const float* __restrict__ conv2_b)
{
  int b = blockIdx.x * blockDim.x + threadIdx.x;
  if (b >= NB) return;
  float y[OO];
  #pragma unroll
  for (int o = 0; o < OO; ++o) y[o] = fmaxf(out[b*OO + o] + conv1_b[o], 0.f);
  #pragma unroll
  for (int q = 0; q < OO; ++q) {
    float s = conv2_b[q];
    #pragma unroll
    for (int o = 0; o < OO; ++o) s += conv2_w[q*OO + o] * y[o];
    out[b*OO + q] = s;
  }
}

extern "C" void kernel_launch(void* const* d_in, const int* in_sizes, int n_in,
                              void* d_out, int out_size, void* d_ws, size_t ws_size,
                              hipStream_t stream) {
  const float* node_resnet = (const float*)d_in[0];
  const float* pos      = (const float*)d_in[1];
  const int*   attmat   = (const int*)  d_in[2];
  const float* link_w1  = (const float*)d_in[3];
  const float* link_b1  = (const float*)d_in[4];
  const float* link_w2  = (const float*)d_in[5];
  const float* link_b2  = (const float*)d_in[6];
  const float* msg_Wh   = (const float*)d_in[7];
  const float* msg_We   = (const float*)d_in[8];
  const float* msg_b    = (const float*)d_in[9];
  const float* gru_Wih  = (const float*)d_in[10];
  const float* gru_Whh  = (const float*)d_in[11];
  const float* gru_bih  = (const float*)d_in[12];
  const float* gru_bhh  = (const float*)d_in[13];
  const float* conv1_w  = (const float*)d_in[14];
  const float* conv1_b  = (const float*)d_in[15];
  const float* conv2_w  = (const float*)d_in[16];
  const float* conv2_b  = (const float*)d_in[17];
  float* out = (float*)d_out;

  // out doubles as the conv1 pre-activation accumulator; zero it each call
  // (harness does not re-poison between graph replays).
  hipMemsetAsync(out, 0, (size_t)NB*OO*sizeof(float), stream);
  gnn_main<<<BT_TOTAL/G, BLK, 0, stream>>>(node_resnet, pos, attmat,
                                           link_w1, link_b1, link_w2, link_b2,
                                           msg_Wh, msg_We, msg_b,
                                           gru_Wih, gru_Whh, gru_bih, gru_bhh,
                                           conv1_w, out);
  gnn_final<<<(NB + 255)/256, 256, 0, stream>>>(out, conv1_b, conv2_w, conv2_b);
}

// Round 2
// 1763.508 us; speedup vs baseline: 1.8873x; 1.8873x over previous
//
#include <hip/hip_runtime.h>
#include <math.h>

// Sizes (fixed by the reference)
#define NB 1024      // batch
#define TT 5         // seq len
#define NN 6         // nodes
#define DD 192       // node feat
#define EE 12        // edge feat
#define MM 12        // message size
#define LL 512       // link hidden
#define OO 6         // out channels
#define BT_TOTAL (NB*TT)   // 5120
#define G 8          // (b,t) pairs per workgroup
#define BLK 384      // 6 waves

__device__ __forceinline__ float sigmoidf_(float x) { return 1.f / (1.f + __expf(-x)); }
__device__ __forceinline__ float dot4(float4 a, float4 b) {
  return a.x*b.x + a.y*b.y + a.z*b.z + a.w*b.w;
}

// One WG handles G consecutive (b,t) pairs end-to-end (both propagate layers),
// all state in LDS; conv1 partial sums are atomically added into out_accum.
__global__ __launch_bounds__(BLK, 3)
void gnn_main(const float* __restrict__ node_resnet,
              const float* __restrict__ pos,
              const int*   __restrict__ attmat,
              const float* __restrict__ link_w1, const float* __restrict__ link_b1,
              const float* __restrict__ link_w2, const float* __restrict__ link_b2,
              const float* __restrict__ msg_Wh,  const float* __restrict__ msg_We,
              const float* __restrict__ msg_b,
              const float* __restrict__ gru_Wih, const float* __restrict__ gru_Whh,
              const float* __restrict__ gru_bih, const float* __restrict__ gru_bhh,
              const float* __restrict__ conv1_w,
              float* __restrict__ out_accum)
{
  __shared__ __align__(16) float sh_h[G][NN][DD+4];   // [p][n][d], padded row
  __shared__ __align__(16) float sh_e[G][36][EE];     // [p][edge(i*6+j)][c]
  __shared__ __align__(16) float sh_m[G][36][MM];
  __shared__ __align__(16) float sh_mh[G][NN][MM];    // [p][j][o], includes msg_b
  __shared__            float sh_adj[G][36];
  __shared__ __align__(16) float sh_msum[G][NN][MM];  // [p][i][o]

  const int tid = threadIdx.x;
  const int p_base = blockIdx.x * G;

  // ---- Phase 0: load h (coalesced) and build edge features ----
  const float* hsrc = node_resnet + (size_t)p_base * (DD*NN);
  for (int i = tid; i < G*DD*NN; i += BLK) {
    int p = i / (DD*NN), rem = i % (DD*NN);
    int d = rem / NN, n = rem % NN;
    sh_h[p][n][d] = hsrc[i];
  }
  for (int idx = tid; idx < G*36*EE; idx += BLK) {
    int p = idx / (36*EE), rem = idx % (36*EE);
    int edge = rem / EE, c = rem % EE;
    int ii = edge / NN, jj = edge % NN;
    int bt = p_base + p;
    int srcn = (c < 6) ? ii : jj;
    int cc   = (c < 6) ? c  : c - 6;
    float v = pos[bt*36 + srcn*6 + cc];
    bool msk = (attmat[bt*36 + edge] == 1) && (ii != jj);
    sh_e[p][edge][c] = msk ? v : 0.f;
  }
  __syncthreads();

  for (int layer = 0; layer < 2; ++layer) {
    // ---- Phase A: adj = sigmoid(link(edge_state)); 1 thread per edge ----
    const float* es_base = (layer == 0) ? &sh_e[0][0][0] : &sh_m[0][0][0];
    if (tid < G*36) {
      int p = tid / 36, edge = tid % 36;
      const float4* ev4 = (const float4*)(es_base + (p*36 + edge)*EE);
      float4 e0 = ev4[0], e1 = ev4[1], e2 = ev4[2];
      const float4* w14 = (const float4*)link_w1;
      float logit = link_b2[0];
      #pragma unroll 4
      for (int l = 0; l < LL; ++l) {
        float a = link_b1[l]
                + dot4(w14[l*3+0], e0) + dot4(w14[l*3+1], e1) + dot4(w14[l*3+2], e2);
        logit += link_w2[l] * fmaxf(a, 0.f);
      }
      sh_adj[p][edge] = sigmoidf_(logit);
    }
    // ---- Phase B: mh[p][j][o] = msg_b[o] + Wh[o,:]·h[p][j,:]  (disjoint from A) ----
    for (int idx = tid; idx < G*NN*MM; idx += BLK) {
      int p = idx / (NN*MM), rem = idx % (NN*MM);
      int j = rem / MM, o = rem % MM;
      const float4* wrow = (const float4*)(msg_Wh + (size_t)o*DD);
      const float4* hrow = (const float4*)(&sh_h[p][j][0]);
      float acc = msg_b[o];
      #pragma unroll 8
      for (int d4 = 0; d4 < DD/4; ++d4) acc += dot4(wrow[d4], hrow[d4]);
      sh_mh[p][j][o] = acc;
    }
    __syncthreads();

    // ---- Phase C: m = adj * relu(mh_j + We·e) ----
    for (int idx = tid; idx < G*36*MM; idx += BLK) {
      int p = idx / (36*MM), rem = idx % (36*MM);
      int edge = rem / MM, o = rem % MM;
      int jj = edge % NN;
      const float4* we4 = (const float4*)(msg_We + o*EE);
      const float4* ev4 = (const float4*)(&sh_e[p][edge][0]);
      float me = dot4(we4[0], ev4[0]) + dot4(we4[1], ev4[1]) + dot4(we4[2], ev4[2]);
      sh_m[p][edge][o] = sh_adj[p][edge] * fmaxf(sh_mh[p][jj][o] + me, 0.f);
    }
    __syncthreads();

    // ---- Phase D: msum[p][i][o] = sum_j m[p][(i,j)][o] ----
    for (int idx = tid; idx < G*NN*MM; idx += BLK) {
      int p = idx / (NN*MM), rem = idx % (NN*MM);
      int i = rem / MM, o = rem % MM;
      float s = 0.f;
      #pragma unroll
      for (int j = 0; j < NN; ++j) s += sh_m[p][i*NN + j][o];
      sh_msum[p][i][o] = s;
    }
    __syncthreads();

    // ---- Phase E: GRU, chunked (3 x 8 rows) so accumulators stay in VGPRs ----
    // thread (t = col 0..191, rg = row-half 0/1); rows rg*24 + chunk*8 .. +7.
    // Per chunk: compute gates (reads h rows of this chunk only) -> barrier ->
    // in-place h write (next chunk reads disjoint rows -> race-free).
    {
      const int t  = tid % DD;
      const int rg = tid / DD;
      const float4* wi1 = (const float4*)(gru_Wih + (size_t)t*MM);
      const float4* wi2 = (const float4*)(gru_Wih + (size_t)(DD + t)*MM);
      const float4* wi3 = (const float4*)(gru_Wih + (size_t)(2*DD + t)*MM);
      const float4* w1r = (const float4*)(gru_Whh + (size_t)t*DD);
      const float4* w2r = (const float4*)(gru_Whh + (size_t)(DD + t)*DD);
      const float4* w3r = (const float4*)(gru_Whh + (size_t)(2*DD + t)*DD);
      const float bA = gru_bih[t]        + gru_bhh[t];
      const float bB = gru_bih[DD + t]   + gru_bhh[DD + t];
      const float bC = gru_bih[2*DD + t];
      const float bD = gru_bhh[2*DD + t];

      #pragma unroll 1
      for (int chunk = 0; chunk < 3; ++chunk) {
        const int row0 = rg*24 + chunk*8;
        // per-row LDS base pointers (hoists /6 %6 out of inner loops)
        const float4* h4[8];
        const float4* x4[8];
        float*        hw[8];
        #pragma unroll
        for (int r = 0; r < 8; ++r) {
          int row = row0 + r, p = row / NN, n = row % NN;
          h4[r] = (const float4*)&sh_h[p][n][0];
          x4[r] = (const float4*)&sh_msum[p][n][0];
          hw[r] = &sh_h[p][n][t];
        }
        float A[8], Bv[8], Cv[8], Dv[8];
        #pragma unroll
        for (int r = 0; r < 8; ++r) { A[r]=bA; Bv[r]=bB; Cv[r]=bC; Dv[r]=bD; }

        {   // gi = msum @ Wih.T   (transient weight regs)
          float4 a10=wi1[0], a11=wi1[1], a12=wi1[2];
          float4 a20=wi2[0], a21=wi2[1], a22=wi2[2];
          float4 a30=wi3[0], a31=wi3[1], a32=wi3[2];
          #pragma unroll
          for (int r = 0; r < 8; ++r) {
            float4 x0=x4[r][0], x1=x4[r][1], x2=x4[r][2];
            A[r]  += dot4(a10,x0)+dot4(a11,x1)+dot4(a12,x2);
            Bv[r] += dot4(a20,x0)+dot4(a21,x1)+dot4(a22,x2);
            Cv[r] += dot4(a30,x0)+dot4(a31,x1)+dot4(a32,x2);
          }
        }
        // gh = h @ Whh.T : stream 3 Whh rows, h via LDS broadcast
        for (int d4 = 0; d4 < DD/4; ++d4) {
          float4 w1 = w1r[d4], w2 = w2r[d4], w3 = w3r[d4];
          #pragma unroll
          for (int r = 0; r < 8; ++r) {
            float4 hv = h4[r][d4];
            A[r] += dot4(w1,hv); Bv[r] += dot4(w2,hv); Dv[r] += dot4(w3,hv);
          }
        }
        __syncthreads();   // all reads of this chunk's h rows complete
        #pragma unroll
        for (int r = 0; r < 8; ++r) {
          float hold = *hw[r];
          float rr  = sigmoidf_(A[r]);
          float zz  = sigmoidf_(Bv[r]);
          float nn2 = tanhf(Cv[r] + rr*Dv[r]);
          *hw[r] = (1.f - zz)*nn2 + zz*hold;
        }
      }
      __syncthreads();  // h fully updated before next layer / conv
    }
  }

  // ---- Conv1 partials: 48 tasks (p,o), 8 lanes each; atomicAdd into out_accum ----
  {
    int task = tid >> 3, sub = tid & 7;
    int p = task / OO, o = task % OO;
    int bt = p_base + p;
    int b = bt / TT, t = bt % TT;
    float acc = 0.f;
    for (int k = sub; k < NN*DD; k += 8) {
      int n = k / DD, d = k % DD;
      acc += sh_h[p][n][d] * conv1_w[((o*DD + d)*TT + t)*NN + n];
    }
    acc += __shfl_xor(acc, 1);
    acc += __shfl_xor(acc, 2);
    acc += __shfl_xor(acc, 4);
    if (sub == 0) atomicAdd(&out_accum[b*OO + o], acc);
  }
}

// Finalize: out = (relu(acc + conv1_b)) @ conv2_w.T + conv2_b, in place on d_out
__global__ void gnn_final(float* __restrict__ out,
                          const float* __restrict__ conv1_b,
                          const float* __restrict__ conv2_w,
                          const float* __restrict__ conv2_b)
{
  int b = blockIdx.x * blockDim.x + threadIdx.x;
  if (b >= NB) return;
  float y[OO];
  #pragma unroll
  for (int o = 0; o < OO; ++o) y[o] = fmaxf(out[b*OO + o] + conv1_b[o], 0.f);
  #pragma unroll
  for (int q = 0; q < OO; ++q) {
    float s = conv2_b[q];
    #pragma unroll
    for (int o = 0; o < OO; ++o) s += conv2_w[q*OO + o] * y[o];
    out[b*OO + q] = s;
  }
}

extern "C" void kernel_launch(void* const* d_in, const int* in_sizes, int n_in,
                              void* d_out, int out_size, void* d_ws, size_t ws_size,
                              hipStream_t stream) {
  const float* node_resnet = (const float*)d_in[0];
  const float* pos      = (const float*)d_in[1];
  const int*   attmat   = (const int*)  d_in[2];
  const float* link_w1  = (const float*)d_in[3];
  const float* link_b1  = (const float*)d_in[4];
  const float* link_w2  = (const float*)d_in[5];
  const float* link_b2  = (const float*)d_in[6];
  const float* msg_Wh   = (const float*)d_in[7];
  const float* msg_We   = (const float*)d_in[8];
  const float* msg_b    = (const float*)d_in[9];
  const float* gru_Wih  = (const float*)d_in[10];
  const float* gru_Whh  = (const float*)d_in[11];
  const float* gru_bih  = (const float*)d_in[12];
  const float* gru_bhh  = (const float*)d_in[13];
  const float* conv1_w  = (const float*)d_in[14];
  const float* conv1_b  = (const float*)d_in[15];
  const float* conv2_w  = (const float*)d_in[16];
  const float* conv2_b  = (const float*)d_in[17];
  float* out = (float*)d_out;

  hipMemsetAsync(out, 0, (size_t)NB*OO*sizeof(float), stream);
  gnn_main<<<BT_TOTAL/G, BLK, 0, stream>>>(node_resnet, pos, attmat,
                                           link_w1, link_b1, link_w2, link_b2,
                                           msg_Wh, msg_We, msg_b,
                                           gru_Wih, gru_Whh, gru_bih, gru_bhh,
                                           conv1_w, out);
  gnn_final<<<(NB + 255)/256, 256, 0, stream>>>(out, conv1_b, conv2_w, conv2_b);
}

// Round 3
// 1171.894 us; speedup vs baseline: 2.8401x; 1.5048x over previous
//
#include <hip/hip_runtime.h>
#include <math.h>

// Sizes (fixed by the reference)
#define NB 1024
#define TT 5
#define NN 6
#define DD 192
#define EE 12
#define MM 12
#define LL 512
#define OO 6
#define BT_TOTAL (NB*TT)      // 5120
#define NROW (BT_TOTAL*NN)    // 30720 GRU rows
#define GATE (3*DD)           // 576

__device__ __forceinline__ float sigmoidf_(float x) { return 1.f / (1.f + __expf(-x)); }
__device__ __forceinline__ float dot4(float4 a, float4 b) {
  return a.x*b.x + a.y*b.y + a.z*b.z + a.w*b.w;
}

// ---------------------------------------------------------------- k_transpose
// WT[k][j] = Whh[j][k]  (so GEMM K-slices are contiguous 576-float rows)
__global__ void k_transpose(const float* __restrict__ Whh, float* __restrict__ WT) {
  int idx = blockIdx.x * 256 + threadIdx.x;     // output-linear
  if (idx >= DD * GATE) return;
  int k = idx / GATE, j = idx % GATE;
  WT[idx] = Whh[(size_t)j * DD + k];
}

// ---------------------------------------------------------------- k_edge
// One WG per (b,t): link MLP -> adj, messages m, msum. Layer 0 also
// transposes node_resnet [d][n] -> wsh [n][d].
#define EBLK 320
template<int LAYER>
__global__ __launch_bounds__(EBLK, 5)
void k_edge(const float* __restrict__ node_resnet,
            const float* __restrict__ pos, const int* __restrict__ attmat,
            const float* __restrict__ link_w1, const float* __restrict__ link_b1,
            const float* __restrict__ link_w2, const float* __restrict__ link_b2,
            const float* __restrict__ msg_Wh,  const float* __restrict__ msg_We,
            const float* __restrict__ msg_b,
            float* __restrict__ wsh, float* __restrict__ wsm, float* __restrict__ wsum)
{
  __shared__ __align__(16) float sh_h[NN][DD+4];
  __shared__ __align__(16) float sh_es[36][EE];
  __shared__ __align__(16) float sh_m[36][MM];
  __shared__ __align__(16) float sh_w1[LL][EE];   // 24.6 KB, conflict-free mapping
  __shared__ float sh_b1[LL], sh_w2[LL];
  __shared__ float sh_adj[36];
  __shared__ __align__(16) float sh_mh[NN][MM];
  const int tid = threadIdx.x;
  const int bt = blockIdx.x;

  // h -> LDS as [n][d]
  if (LAYER == 0) {
    for (int i = tid; i < DD*NN; i += EBLK) {
      int d = i / NN, n = i % NN;
      sh_h[n][d] = node_resnet[(size_t)bt*DD*NN + i];   // coalesced read
    }
  } else {
    for (int i = tid; i < NN*DD; i += EBLK)
      sh_h[i/DD][i%DD] = wsh[(size_t)bt*NN*DD + i];
  }
  // edge state -> LDS
  if (LAYER == 0) {
    for (int idx = tid; idx < 36*EE; idx += EBLK) {
      int e = idx / EE, c = idx % EE;
      int i_ = e / NN, j_ = e % NN;
      int srcn = (c < 6) ? i_ : j_;
      int cc   = (c < 6) ? c  : c - 6;
      float v = pos[bt*36 + srcn*6 + cc];
      bool msk = (attmat[bt*36 + e] == 1) && (i_ != j_);
      sh_es[e][c] = msk ? v : 0.f;
    }
  } else {
    for (int idx = tid; idx < 36*MM; idx += EBLK)
      sh_es[idx/MM][idx%MM] = wsm[(size_t)bt*36*MM + idx];
  }
  // stage link weights (coalesced)
  for (int i = tid; i < LL*EE; i += EBLK) sh_w1[i/EE][i%EE] = link_w1[i];
  for (int i = tid; i < LL; i += EBLK) { sh_b1[i] = link_b1[i]; sh_w2[i] = link_w2[i]; }
  __syncthreads();

  if (LAYER == 0) {   // persist transposed h for k_gru / layer 1 / conv
    for (int i = tid; i < NN*DD; i += EBLK)
      wsh[(size_t)bt*NN*DD + i] = sh_h[i/DD][i%DD];
  }

  // link MLP: 36 edges x 8 lanes; lane handles l = lane + 8u (8 consecutive
  // rows per step -> 8 distinct LDS bank groups, conflict-free)
  if (tid < 288) {
    int e = tid >> 3, lane = tid & 7;
    const float4* ev = (const float4*)&sh_es[e][0];
    float4 e0 = ev[0], e1 = ev[1], e2 = ev[2];
    float p = 0.f;
    #pragma unroll 4
    for (int u = 0; u < 64; ++u) {
      int l = lane + (u << 3);
      const float4* w = (const float4*)&sh_w1[l][0];
      float a = sh_b1[l] + dot4(w[0],e0) + dot4(w[1],e1) + dot4(w[2],e2);
      p += sh_w2[l] * fmaxf(a, 0.f);
    }
    p += __shfl_xor(p, 1); p += __shfl_xor(p, 2); p += __shfl_xor(p, 4);
    if (lane == 0) sh_adj[e] = sigmoidf_(p + link_b2[0]);
  }
  // mh[n][o] = msg_b[o] + Wh[o,:] . h[n,:]
  if (tid < NN*MM) {
    int n = tid / MM, o = tid % MM;
    const float4* wrow = (const float4*)(msg_Wh + (size_t)o*DD);
    const float4* hrow = (const float4*)&sh_h[n][0];
    float acc = msg_b[o];
    #pragma unroll 8
    for (int d4 = 0; d4 < DD/4; ++d4) acc += dot4(wrow[d4], hrow[d4]);
    sh_mh[n][o] = acc;
  }
  __syncthreads();

  // m = adj * relu(mh_j + We.e); write edge_state for next layer
  for (int idx = tid; idx < 36*MM; idx += EBLK) {
    int e = idx / MM, o = idx % MM;
    int j_ = e % NN;
    const float4* we = (const float4*)(msg_We + o*EE);
    const float4* ev = (const float4*)&sh_es[e][0];
    float me = dot4(we[0],ev[0]) + dot4(we[1],ev[1]) + dot4(we[2],ev[2]);
    float mv = sh_adj[e] * fmaxf(sh_mh[j_][o] + me, 0.f);
    sh_m[e][o] = mv;
    wsm[(size_t)bt*36*MM + idx] = mv;
  }
  __syncthreads();
  if (tid < NN*MM) {
    int i_ = tid / MM, o = tid % MM;
    float s = 0.f;
    #pragma unroll
    for (int j = 0; j < NN; ++j) s += sh_m[i_*NN + j][o];
    wsum[(size_t)bt*NN*MM + tid] = s;
  }
}

// ---------------------------------------------------------------- k_gru
// GEMM-shaped GRU: M-tile = 16 rows x N = 576 (thread owns cols c, 192+c,
// 384+c for 8 rows -> 32 accumulators). WT staged in LDS per K-slice
// (coalesced); h rows staged once (broadcast reads). In-place h update
// (row-local -> no cross-WG hazard).
#define GBLK 384
#define MT 16
__global__ __launch_bounds__(GBLK, 5)
void k_gru(const float* __restrict__ WT,
           const float* __restrict__ gru_Wih,
           const float* __restrict__ gru_bih, const float* __restrict__ gru_bhh,
           const float* __restrict__ wsum,
           float* __restrict__ wsh)
{
  __shared__ __align__(16) float sh_ht[MT][DD];   // 12.3 KB
  __shared__ __align__(16) float sh_x[MT][MM];    // 768 B
  __shared__ __align__(16) float sh_B[8][GATE];   // 18.4 KB K-slice
  const int tid = threadIdx.x;
  const int row0 = blockIdx.x * MT;
  const int c  = tid % DD;
  const int rg = tid / DD;      // 0,1 -> rows rg*8 .. +7

  for (int i = tid; i < MT*DD; i += GBLK)
    sh_ht[i/DD][i%DD] = wsh[(size_t)row0*DD + i];
  for (int i = tid; i < MT*MM; i += GBLK)
    sh_x[i/MM][i%MM] = wsum[(size_t)row0*MM + i];
  __syncthreads();

  float A[8], Bv[8], Cv[8], Dv[8];
  {
    const float bA = gru_bih[c]        + gru_bhh[c];
    const float bB = gru_bih[DD + c]   + gru_bhh[DD + c];
    const float bC = gru_bih[2*DD + c];
    const float bD = gru_bhh[2*DD + c];
    const float4* wi1 = (const float4*)(gru_Wih + (size_t)c*MM);
    const float4* wi2 = (const float4*)(gru_Wih + (size_t)(DD + c)*MM);
    const float4* wi3 = (const float4*)(gru_Wih + (size_t)(2*DD + c)*MM);
    float4 a0=wi1[0], a1=wi1[1], a2=wi1[2];
    float4 b0=wi2[0], b1=wi2[1], b2=wi2[2];
    float4 c0=wi3[0], c1=wi3[1], c2=wi3[2];
    #pragma unroll
    for (int m = 0; m < 8; ++m) {
      const float4* x = (const float4*)&sh_x[rg*8 + m][0];
      float4 x0=x[0], x1=x[1], x2=x[2];
      A[m]  = bA + dot4(a0,x0)+dot4(a1,x1)+dot4(a2,x2);
      Bv[m] = bB + dot4(b0,x0)+dot4(b1,x1)+dot4(b2,x2);
      Cv[m] = bC + dot4(c0,x0)+dot4(c1,x1)+dot4(c2,x2);
      Dv[m] = bD;
    }
  }

  for (int k0 = 0; k0 < DD; k0 += 8) {
    __syncthreads();   // previous slice fully consumed
    {  // stage WT[k0..k0+8)[0..576): 4608 floats = 3 float4/thread, coalesced
      const float4* src = (const float4*)(WT + (size_t)k0*GATE);
      float4* dst = (float4*)&sh_B[0][0];
      #pragma unroll
      for (int j = 0; j < 3; ++j) dst[tid*3 + j] = src[tid*3 + j];
    }
    __syncthreads();
    #pragma unroll
    for (int kk = 0; kk < 8; kk += 4) {
      float bA[4], bB[4], bD[4];
      #pragma unroll
      for (int q = 0; q < 4; ++q) {
        bA[q] = sh_B[kk+q][c];
        bB[q] = sh_B[kk+q][DD + c];
        bD[q] = sh_B[kk+q][2*DD + c];
      }
      #pragma unroll
      for (int m = 0; m < 8; ++m) {
        float4 hv = *(const float4*)&sh_ht[rg*8 + m][k0 + kk];
        A[m]  += bA[0]*hv.x + bA[1]*hv.y + bA[2]*hv.z + bA[3]*hv.w;
        Bv[m] += bB[0]*hv.x + bB[1]*hv.y + bB[2]*hv.z + bB[3]*hv.w;
        Dv[m] += bD[0]*hv.x + bD[1]*hv.y + bD[2]*hv.z + bD[3]*hv.w;
      }
    }
  }
  #pragma unroll
  for (int m = 0; m < 8; ++m) {
    int row = row0 + rg*8 + m;
    float hold = sh_ht[rg*8 + m][c];
    float rr  = sigmoidf_(A[m]);
    float zz  = sigmoidf_(Bv[m]);
    float nn2 = tanhf(Cv[m] + rr*Dv[m]);
    wsh[(size_t)row*DD + c] = (1.f - zz)*nn2 + zz*hold;   // coalesced
  }
}

// ---------------------------------------------------------------- k_conv
// One WG per batch b: out[b,:] = conv2( relu( conv1(h_b) + b1 ) ) + b2.
// conv1_w streamed coalesced, h_b staged in LDS. Writes d_out exactly once.
#define CBLK 256
__global__ __launch_bounds__(CBLK, 4)
void k_conv(const float* __restrict__ wsh,
            const float* __restrict__ conv1_w, const float* __restrict__ conv1_b,
            const float* __restrict__ conv2_w, const float* __restrict__ conv2_b,
            float* __restrict__ out)
{
  __shared__ float sh_h[TT*NN][DD+4];   // 30 x 196
  __shared__ float red[CBLK/64][OO];
  const int tid = threadIdx.x;
  const int b = blockIdx.x;
  for (int i = tid; i < TT*NN*DD; i += CBLK)
    sh_h[i/DD][i%DD] = wsh[(size_t)b*TT*NN*DD + i];
  __syncthreads();
  float acc[OO];
  #pragma unroll
  for (int o = 0; o < OO; ++o) acc[o] = 0.f;
  #pragma unroll
  for (int o = 0; o < OO; ++o) {
    const float* wo = conv1_w + (size_t)o*DD*TT*NN;
    for (int u = tid; u < DD*TT*NN; u += CBLK) {
      int n = u % NN; int t = (u / NN) % TT; int d = u / (NN*TT);
      acc[o] += wo[u] * sh_h[t*NN + n][d];
    }
  }
  #pragma unroll
  for (int o = 0; o < OO; ++o) {
    float v = acc[o];
    v += __shfl_xor(v, 1);  v += __shfl_xor(v, 2);  v += __shfl_xor(v, 4);
    v += __shfl_xor(v, 8);  v += __shfl_xor(v, 16); v += __shfl_xor(v, 32);
    acc[o] = v;
  }
  if ((tid & 63) == 0) {
    #pragma unroll
    for (int o = 0; o < OO; ++o) red[tid >> 6][o] = acc[o];
  }
  __syncthreads();
  if (tid == 0) {
    float y[OO];
    #pragma unroll
    for (int o = 0; o < OO; ++o) {
      float s = conv1_b[o];
      #pragma unroll
      for (int w = 0; w < CBLK/64; ++w) s += red[w][o];
      y[o] = fmaxf(s, 0.f);
    }
    #pragma unroll
    for (int q = 0; q < OO; ++q) {
      float s = conv2_b[q];
      #pragma unroll
      for (int o = 0; o < OO; ++o) s += conv2_w[q*OO + o] * y[o];
      out[b*OO + q] = s;
    }
  }
}

// ---------------------------------------------------------------- launch
extern "C" void kernel_launch(void* const* d_in, const int* in_sizes, int n_in,
                              void* d_out, int out_size, void* d_ws, size_t ws_size,
                              hipStream_t stream) {
  const float* node_resnet = (const float*)d_in[0];
  const float* pos      = (const float*)d_in[1];
  const int*   attmat   = (const int*)  d_in[2];
  const float* link_w1  = (const float*)d_in[3];
  const float* link_b1  = (const float*)d_in[4];
  const float* link_w2  = (const float*)d_in[5];
  const float* link_b2  = (const float*)d_in[6];
  const float* msg_Wh   = (const float*)d_in[7];
  const float* msg_We   = (const float*)d_in[8];
  const float* msg_b    = (const float*)d_in[9];
  const float* gru_Wih  = (const float*)d_in[10];
  const float* gru_Whh  = (const float*)d_in[11];
  const float* gru_bih  = (const float*)d_in[12];
  const float* gru_bhh  = (const float*)d_in[13];
  const float* conv1_w  = (const float*)d_in[14];
  const float* conv1_b  = (const float*)d_in[15];
  const float* conv2_w  = (const float*)d_in[16];
  const float* conv2_b  = (const float*)d_in[17];
  float* out = (float*)d_out;

  // ws layout (floats): WT | h | m | msum  == 34.4 MB total
  float* WT   = (float*)d_ws;
  float* wsh  = WT  + (size_t)DD*GATE;
  float* wsm  = wsh + (size_t)BT_TOTAL*NN*DD;
  float* wsum = wsm + (size_t)BT_TOTAL*36*MM;

  k_transpose<<<(DD*GATE + 255)/256, 256, 0, stream>>>(gru_Whh, WT);
  k_edge<0><<<BT_TOTAL, EBLK, 0, stream>>>(node_resnet, pos, attmat,
      link_w1, link_b1, link_w2, link_b2, msg_Wh, msg_We, msg_b, wsh, wsm, wsum);
  k_gru<<<NROW/MT, GBLK, 0, stream>>>(WT, gru_Wih, gru_bih, gru_bhh, wsum, wsh);
  k_edge<1><<<BT_TOTAL, EBLK, 0, stream>>>(node_resnet, pos, attmat,
      link_w1, link_b1, link_w2, link_b2, msg_Wh, msg_We, msg_b, wsh, wsm, wsum);
  k_gru<<<NROW/MT, GBLK, 0, stream>>>(WT, gru_Wih, gru_bih, gru_bhh, wsum, wsh);
  k_conv<<<NB, CBLK, 0, stream>>>(wsh, conv1_w, conv1_b, conv2_w, conv2_b, out);
}

// Round 4
// 442.367 us; speedup vs baseline: 7.5238x; 2.6491x over previous
//
#include <hip/hip_runtime.h>
#include <math.h>

// Sizes (fixed by the reference)
#define NB 1024
#define TT 5
#define NN 6
#define DD 192
#define EE 12
#define MM 12
#define LL 512
#define OO 6
#define BT_TOTAL (NB*TT)      // 5120
#define NROW (BT_TOTAL*NN)    // 30720 GRU rows
#define GATE (3*DD)           // 576
#define GOUT 768              // logical GEMM N: [r|z|inn|hn]
#define KPAD 224              // 12 (x) + 192 (h) + 20 zero-pad
#define NKT (KPAD/32)         // 7 k-tiles
#define NJT (GOUT/16)         // 48 n-tiles
#define APITCH 232            // LDS row pitch in bf16 (464 B -> low bank conflicts)

typedef __attribute__((ext_vector_type(8))) short bf16x8;
typedef __attribute__((ext_vector_type(4))) float f32x4;

__device__ __forceinline__ float sigmoidf_(float x) { return 1.f / (1.f + __expf(-x)); }
__device__ __forceinline__ float dot4(float4 a, float4 b) {
  return a.x*b.x + a.y*b.y + a.z*b.z + a.w*b.w;
}
__device__ __forceinline__ unsigned short f2bf(float f) {
  unsigned int u = __float_as_uint(f);
  unsigned int r = (u + 0x7FFFu + ((u >> 16) & 1u)) >> 16;
  return (unsigned short)r;
}
__device__ __forceinline__ float bf2f(unsigned short s) {
  return __uint_as_float(((unsigned int)s) << 16);
}

// ---------------------------------------------------------------- k_pack
// Pack W' [KPAD x GOUT] into MFMA B-fragment layout, split hi/lo bf16.
// W'[k][c]: c<384 (r,z): k<12 ? Wih[c][k] : Whh[c][k-12]
//           c in [384,576) (inn): k<12 ? Wih[c][k] : 0
//           c in [576,768) (hn):  k<12 ? 0 : Whh[c-192][k-12]
// Fragment: elem idx = ((j*NKT+kt)*64 + lane)*8 + e, k = kt*32+(lane>>4)*8+e,
// c = j*16 + (lane&15).  Also emits fused bias768.
__global__ void k_pack(const float* __restrict__ Wih, const float* __restrict__ Whh,
                       const float* __restrict__ bih, const float* __restrict__ bhh,
                       unsigned short* __restrict__ Bhi, unsigned short* __restrict__ Blo,
                       float* __restrict__ bias768)
{
  int idx = blockIdx.x * 256 + threadIdx.x;
  if (idx < GOUT) {
    int c = idx; float b;
    if (c < 384)      b = bih[c] + bhh[c];
    else if (c < 576) b = bih[c];
    else              b = bhh[c - 192];
    bias768[c] = b;
  }
  if (idx >= NJT*NKT*512) return;
  int e = idx & 7, l = (idx >> 3) & 63;
  int rem = idx >> 9, kt = rem % NKT, j = rem / NKT;
  int k = kt*32 + ((l >> 4) << 3) + e;
  int c = j*16 + (l & 15);
  float v = 0.f;
  if (k < 204) {
    if (c < 384)      v = (k < 12) ? Wih[c*MM + k] : Whh[(size_t)c*DD + (k-12)];
    else if (c < 576) v = (k < 12) ? Wih[c*MM + k] : 0.f;
    else              v = (k < 12) ? 0.f : Whh[(size_t)(c-192)*DD + (k-12)];
  }
  unsigned short hi = f2bf(v);
  Bhi[idx] = hi;
  Blo[idx] = f2bf(v - bf2f(hi));
}

// ---------------------------------------------------------------- k_edge
// One WG per (b,t): link MLP -> adj, messages m, msum.
// NOTE: me term uses ORIGINAL edge features e in BOTH layers (reference);
// only the link input switches to m for layer 1.
#define EBLK 320
template<int LAYER>
__global__ __launch_bounds__(EBLK, 5)
void k_edge(const float* __restrict__ node_resnet,
            const float* __restrict__ pos, const int* __restrict__ attmat,
            const float* __restrict__ link_w1, const float* __restrict__ link_b1,
            const float* __restrict__ link_w2, const float* __restrict__ link_b2,
            const float* __restrict__ msg_Wh,  const float* __restrict__ msg_We,
            const float* __restrict__ msg_b,
            float* __restrict__ wsh, float* __restrict__ wsm, float* __restrict__ wsum)
{
  __shared__ __align__(16) float sh_h[NN][DD+4];
  __shared__ __align__(16) float sh_e[36][EE];    // original edge features (me term)
  __shared__ __align__(16) float sh_es[36][EE];   // link input (e for L0, m for L1)
  __shared__ __align__(16) float sh_m[36][MM];
  __shared__ __align__(16) float sh_w1[LL][EE];   // 24.6 KB
  __shared__ float sh_b1[LL], sh_w2[LL];
  __shared__ float sh_adj[36];
  __shared__ __align__(16) float sh_mh[NN][MM];
  const int tid = threadIdx.x;
  const int bt = blockIdx.x;

  // h -> LDS as [n][d]
  if (LAYER == 0) {
    for (int i = tid; i < DD*NN; i += EBLK) {
      int d = i / NN, n = i % NN;
      sh_h[n][d] = node_resnet[(size_t)bt*DD*NN + i];   // coalesced read
    }
  } else {
    for (int i = tid; i < NN*DD; i += EBLK)
      sh_h[i/DD][i%DD] = wsh[(size_t)bt*NN*DD + i];
  }
  // original edge features (both layers)
  for (int idx = tid; idx < 36*EE; idx += EBLK) {
    int e = idx / EE, c = idx % EE;
    int i_ = e / NN, j_ = e % NN;
    int srcn = (c < 6) ? i_ : j_;
    int cc   = (c < 6) ? c  : c - 6;
    float v = pos[bt*36 + srcn*6 + cc];
    bool msk = (attmat[bt*36 + e] == 1) && (i_ != j_);
    sh_e[e][c] = msk ? v : 0.f;
  }
  if (LAYER == 1) {
    for (int idx = tid; idx < 36*MM; idx += EBLK)
      sh_es[idx/MM][idx%MM] = wsm[(size_t)bt*36*MM + idx];
  }
  // stage link weights (coalesced)
  for (int i = tid; i < LL*EE; i += EBLK) sh_w1[i/EE][i%EE] = link_w1[i];
  for (int i = tid; i < LL; i += EBLK) { sh_b1[i] = link_b1[i]; sh_w2[i] = link_w2[i]; }
  __syncthreads();

  if (LAYER == 0) {   // persist transposed h for k_gru / layer 1 / conv
    for (int i = tid; i < NN*DD; i += EBLK)
      wsh[(size_t)bt*NN*DD + i] = sh_h[i/DD][i%DD];
  }

  // link MLP: 36 edges x 8 lanes; lane handles l = lane + 8u
  if (tid < 288) {
    int e = tid >> 3, lane = tid & 7;
    const float4* ev = (LAYER == 0) ? (const float4*)&sh_e[e][0]
                                    : (const float4*)&sh_es[e][0];
    float4 e0 = ev[0], e1 = ev[1], e2 = ev[2];
    float p = 0.f;
    #pragma unroll 4
    for (int u = 0; u < 64; ++u) {
      int l = lane + (u << 3);
      const float4* w = (const float4*)&sh_w1[l][0];
      float a = sh_b1[l] + dot4(w[0],e0) + dot4(w[1],e1) + dot4(w[2],e2);
      p += sh_w2[l] * fmaxf(a, 0.f);
    }
    p += __shfl_xor(p, 1); p += __shfl_xor(p, 2); p += __shfl_xor(p, 4);
    if (lane == 0) sh_adj[e] = sigmoidf_(p + link_b2[0]);
  }
  // mh[n][o] = msg_b[o] + Wh[o,:] . h[n,:]
  if (tid < NN*MM) {
    int n = tid / MM, o = tid % MM;
    const float4* wrow = (const float4*)(msg_Wh + (size_t)o*DD);
    const float4* hrow = (const float4*)&sh_h[n][0];
    float acc = msg_b[o];
    #pragma unroll 8
    for (int d4 = 0; d4 < DD/4; ++d4) acc += dot4(wrow[d4], hrow[d4]);
    sh_mh[n][o] = acc;
  }
  __syncthreads();

  // m = adj * relu(mh_j + We.e_orig); write edge_state for next layer
  for (int idx = tid; idx < 36*MM; idx += EBLK) {
    int e = idx / MM, o = idx % MM;
    int j_ = e % NN;
    const float4* we = (const float4*)(msg_We + o*EE);
    const float4* ev = (const float4*)&sh_e[e][0];
    float me = dot4(we[0],ev[0]) + dot4(we[1],ev[1]) + dot4(we[2],ev[2]);
    float mv = sh_adj[e] * fmaxf(sh_mh[j_][o] + me, 0.f);
    sh_m[e][o] = mv;
    wsm[(size_t)bt*36*MM + idx] = mv;
  }
  __syncthreads();
  if (tid < NN*MM) {
    int i_ = tid / MM, o = tid % MM;
    float s = 0.f;
    #pragma unroll
    for (int j = 0; j < NN; ++j) s += sh_m[i_*NN + j][o];
    wsum[(size_t)bt*NN*MM + tid] = s;
  }
}

// ---------------------------------------------------------------- k_gru_mfma
// 32 rows/WG, 4 waves. GEMM [32 x 224] x [224 x 768] via mfma 16x16x32 bf16,
// 3-product hi/lo split (fp32-accurate). Wave w owns d-tiles {3w..3w+2}; for
// each it accumulates n-tiles {dt, dt+12, dt+24, dt+36} = r,z,inn,hn -> gates
// combine in-register. h updated in place (rows exclusive to this WG).
#define GMT 32
__global__ __launch_bounds__(256, 2)
void k_gru_mfma(const unsigned short* __restrict__ Bhi,
                const unsigned short* __restrict__ Blo,
                const float* __restrict__ bias768,
                const float* __restrict__ wsum,
                float* __restrict__ wsh)
{
  __shared__ unsigned int sAhi[GMT][APITCH/2];   // bf16 pairs, 464 B pitch
  __shared__ unsigned int sAlo[GMT][APITCH/2];
  const int tid = threadIdx.x;
  const int row0 = blockIdx.x * GMT;

  // stage A = [x(12) | h(192) | 0-pad]: hi/lo bf16
  for (int i = tid; i < GMT*(KPAD/2); i += 256) {
    int r = i / (KPAD/2), kp = i % (KPAD/2);
    int k0 = kp*2, k1 = k0+1;
    int grow = row0 + r;
    float a0 = (k0 < 12) ? wsum[(size_t)grow*MM + k0]
             : (k0 < 204 ? wsh[(size_t)grow*DD + (k0-12)] : 0.f);
    float a1 = (k1 < 12) ? wsum[(size_t)grow*MM + k1]
             : (k1 < 204 ? wsh[(size_t)grow*DD + (k1-12)] : 0.f);
    unsigned short h0 = f2bf(a0), h1 = f2bf(a1);
    unsigned short l0 = f2bf(a0 - bf2f(h0)), l1 = f2bf(a1 - bf2f(h1));
    sAhi[r][kp] = (unsigned int)h0 | ((unsigned int)h1 << 16);
    sAlo[r][kp] = (unsigned int)l0 | ((unsigned int)l1 << 16);
  }
  __syncthreads();

  const int lane = tid & 63;
  const int wid  = tid >> 6;
  const int col  = lane & 15;
  const int quad = lane >> 4;

  f32x4 acc[4][3][2];   // [gate r/z/inn/hn][dt local][row-tile]
  #pragma unroll
  for (int g = 0; g < 4; ++g)
    #pragma unroll
    for (int i = 0; i < 3; ++i)
      #pragma unroll
      for (int rt = 0; rt < 2; ++rt) acc[g][i][rt] = (f32x4)0.f;

  const char* ahb = (const char*)&sAhi[0][0] + col*(APITCH*2) + quad*16;
  const char* alb = (const char*)&sAlo[0][0] + col*(APITCH*2) + quad*16;

  for (int kt = 0; kt < NKT; ++kt) {
    bf16x8 ah0 = *(const bf16x8*)(ahb + kt*64);
    bf16x8 ah1 = *(const bf16x8*)(ahb + 16*(APITCH*2) + kt*64);
    bf16x8 al0 = *(const bf16x8*)(alb + kt*64);
    bf16x8 al1 = *(const bf16x8*)(alb + 16*(APITCH*2) + kt*64);
    #pragma unroll
    for (int g = 0; g < 4; ++g) {
      #pragma unroll
      for (int i = 0; i < 3; ++i) {
        const int j = g*12 + wid*3 + i;
        const size_t off = ((size_t)(j*NKT + kt) << 9) + lane*8;
        bf16x8 bh = *(const bf16x8*)(Bhi + off);
        bf16x8 bl = *(const bf16x8*)(Blo + off);
        acc[g][i][0] = __builtin_amdgcn_mfma_f32_16x16x32_bf16(ah0, bl, acc[g][i][0], 0, 0, 0);
        acc[g][i][0] = __builtin_amdgcn_mfma_f32_16x16x32_bf16(al0, bh, acc[g][i][0], 0, 0, 0);
        acc[g][i][0] = __builtin_amdgcn_mfma_f32_16x16x32_bf16(ah0, bh, acc[g][i][0], 0, 0, 0);
        acc[g][i][1] = __builtin_amdgcn_mfma_f32_16x16x32_bf16(ah1, bl, acc[g][i][1], 0, 0, 0);
        acc[g][i][1] = __builtin_amdgcn_mfma_f32_16x16x32_bf16(al1, bh, acc[g][i][1], 0, 0, 0);
        acc[g][i][1] = __builtin_amdgcn_mfma_f32_16x16x32_bf16(ah1, bh, acc[g][i][1], 0, 0, 0);
      }
    }
  }

  // epilogue: gates in-register; C/D layout row=(quad*4+reg), col=lane&15
  #pragma unroll
  for (int i = 0; i < 3; ++i) {
    const int dt = wid*3 + i;
    const int d  = dt*16 + col;
    const float bR = bias768[d], bZ = bias768[192 + d];
    const float bI = bias768[384 + d], bH = bias768[576 + d];
    #pragma unroll
    for (int rt = 0; rt < 2; ++rt) {
      #pragma unroll
      for (int q = 0; q < 4; ++q) {
        const int grow = row0 + rt*16 + quad*4 + q;
        float r_ = sigmoidf_(acc[0][i][rt][q] + bR);
        float z_ = sigmoidf_(acc[1][i][rt][q] + bZ);
        float n_ = tanhf(acc[2][i][rt][q] + bI + r_*(acc[3][i][rt][q] + bH));
        float hold = wsh[(size_t)grow*DD + d];
        wsh[(size_t)grow*DD + d] = (1.f - z_)*n_ + z_*hold;
      }
    }
  }
}

// ---------------------------------------------------------------- k_conv
#define CBLK 256
__global__ __launch_bounds__(CBLK, 4)
void k_conv(const float* __restrict__ wsh,
            const float* __restrict__ conv1_w, const float* __restrict__ conv1_b,
            const float* __restrict__ conv2_w, const float* __restrict__ conv2_b,
            float* __restrict__ out)
{
  __shared__ float sh_h[TT*NN][DD+4];
  __shared__ float red[CBLK/64][OO];
  const int tid = threadIdx.x;
  const int b = blockIdx.x;
  for (int i = tid; i < TT*NN*DD; i += CBLK)
    sh_h[i/DD][i%DD] = wsh[(size_t)b*TT*NN*DD + i];
  __syncthreads();
  float acc[OO];
  #pragma unroll
  for (int o = 0; o < OO; ++o) acc[o] = 0.f;
  #pragma unroll
  for (int o = 0; o < OO; ++o) {
    const float* wo = conv1_w + (size_t)o*DD*TT*NN;
    for (int u = tid; u < DD*TT*NN; u += CBLK) {
      int n = u % NN; int t = (u / NN) % TT; int d = u / (NN*TT);
      acc[o] += wo[u] * sh_h[t*NN + n][d];
    }
  }
  #pragma unroll
  for (int o = 0; o < OO; ++o) {
    float v = acc[o];
    v += __shfl_xor(v, 1);  v += __shfl_xor(v, 2);  v += __shfl_xor(v, 4);
    v += __shfl_xor(v, 8);  v += __shfl_xor(v, 16); v += __shfl_xor(v, 32);
    acc[o] = v;
  }
  if ((tid & 63) == 0) {
    #pragma unroll
    for (int o = 0; o < OO; ++o) red[tid >> 6][o] = acc[o];
  }
  __syncthreads();
  if (tid == 0) {
    float y[OO];
    #pragma unroll
    for (int o = 0; o < OO; ++o) {
      float s = conv1_b[o];
      #pragma unroll
      for (int w = 0; w < CBLK/64; ++w) s += red[w][o];
      y[o] = fmaxf(s, 0.f);
    }
    #pragma unroll
    for (int q = 0; q < OO; ++q) {
      float s = conv2_b[q];
      #pragma unroll
      for (int o = 0; o < OO; ++o) s += conv2_w[q*OO + o] * y[o];
      out[b*OO + q] = s;
    }
  }
}

// ---------------------------------------------------------------- launch
extern "C" void kernel_launch(void* const* d_in, const int* in_sizes, int n_in,
                              void* d_out, int out_size, void* d_ws, size_t ws_size,
                              hipStream_t stream) {
  const float* node_resnet = (const float*)d_in[0];
  const float* pos      = (const float*)d_in[1];
  const int*   attmat   = (const int*)  d_in[2];
  const float* link_w1  = (const float*)d_in[3];
  const float* link_b1  = (const float*)d_in[4];
  const float* link_w2  = (const float*)d_in[5];
  const float* link_b2  = (const float*)d_in[6];
  const float* msg_Wh   = (const float*)d_in[7];
  const float* msg_We   = (const float*)d_in[8];
  const float* msg_b    = (const float*)d_in[9];
  const float* gru_Wih  = (const float*)d_in[10];
  const float* gru_Whh  = (const float*)d_in[11];
  const float* gru_bih  = (const float*)d_in[12];
  const float* gru_bhh  = (const float*)d_in[13];
  const float* conv1_w  = (const float*)d_in[14];
  const float* conv1_b  = (const float*)d_in[15];
  const float* conv2_w  = (const float*)d_in[16];
  const float* conv2_b  = (const float*)d_in[17];
  float* out = (float*)d_out;

  // ws layout (floats): wsh | wsm | wsum | bias768 | Bhi | Blo  (~34.6 MB)
  float* wsh  = (float*)d_ws;
  float* wsm  = wsh  + (size_t)NROW*DD;          // 5,898,240
  float* wsum = wsm  + (size_t)BT_TOTAL*36*MM;   // +2,211,840
  float* bias = wsum + (size_t)NROW*MM;          // +368,640
  unsigned short* Bhi = (unsigned short*)(bias + GOUT);
  unsigned short* Blo = Bhi + (size_t)NJT*NKT*512;

  k_pack<<<(NJT*NKT*512 + 255)/256, 256, 0, stream>>>(gru_Wih, gru_Whh,
      gru_bih, gru_bhh, Bhi, Blo, bias);
  k_edge<0><<<BT_TOTAL, EBLK, 0, stream>>>(node_resnet, pos, attmat,
      link_w1, link_b1, link_w2, link_b2, msg_Wh, msg_We, msg_b, wsh, wsm, wsum);
  k_gru_mfma<<<NROW/GMT, 256, 0, stream>>>(Bhi, Blo, bias, wsum, wsh);
  k_edge<1><<<BT_TOTAL, EBLK, 0, stream>>>(node_resnet, pos, attmat,
      link_w1, link_b1, link_w2, link_b2, msg_Wh, msg_We, msg_b, wsh, wsm, wsum);
  k_gru_mfma<<<NROW/GMT, 256, 0, stream>>>(Bhi, Blo, bias, wsum, wsh);
  k_conv<<<NB, CBLK, 0, stream>>>(wsh, conv1_w, conv1_b, conv2_w, conv2_b, out);
}

// Round 5
// 348.729 us; speedup vs baseline: 9.5440x; 1.2685x over previous
//
#include <hip/hip_runtime.h>
#include <math.h>

// Sizes (fixed by the reference)
#define NB 1024
#define TT 5
#define NN 6
#define DD 192
#define EE 12
#define MM 12
#define LL 512
#define OO 6
#define BT_TOTAL (NB*TT)      // 5120
#define NROW (BT_TOTAL*NN)    // 30720 GRU rows
#define NEDGE (BT_TOTAL*36)   // 184320 edges
#define GATE (3*DD)           // 576
#define GOUT 768              // GRU GEMM N: [r|z|inn|hn]
#define KPAD 224              // GRU K: 12 + 192 + 20 pad
#define NKT (KPAD/32)         // 7 k-tiles
#define NJT (GOUT/16)         // 48 n-tiles
#define APITCH 232            // GRU A LDS pitch (bf16)

#define EPW 128               // edges per WG in k_link
#define APL 40                // k_link A LDS pitch in bf16 (80 B)

typedef __attribute__((ext_vector_type(8))) short bf16x8;
typedef __attribute__((ext_vector_type(4))) float f32x4;

__device__ __forceinline__ float sigmoidf_(float x) { return 1.f / (1.f + __expf(-x)); }
__device__ __forceinline__ float dot4(float4 a, float4 b) {
  return a.x*b.x + a.y*b.y + a.z*b.z + a.w*b.w;
}
__device__ __forceinline__ unsigned short f2bf(float f) {
  unsigned int u = __float_as_uint(f);
  unsigned int r = (u + 0x7FFFu + ((u >> 16) & 1u)) >> 16;
  return (unsigned short)r;
}
__device__ __forceinline__ float bf2f(unsigned short s) {
  return __uint_as_float(((unsigned int)s) << 16);
}

// ---------------------------------------------------------------- k_pack (GRU W)
__global__ void k_pack(const float* __restrict__ Wih, const float* __restrict__ Whh,
                       const float* __restrict__ bih, const float* __restrict__ bhh,
                       unsigned short* __restrict__ Bhi, unsigned short* __restrict__ Blo,
                       float* __restrict__ bias768)
{
  int idx = blockIdx.x * 256 + threadIdx.x;
  if (idx < GOUT) {
    int c = idx; float b;
    if (c < 384)      b = bih[c] + bhh[c];
    else if (c < 576) b = bih[c];
    else              b = bhh[c - 192];
    bias768[c] = b;
  }
  if (idx >= NJT*NKT*512) return;
  int e = idx & 7, l = (idx >> 3) & 63;
  int rem = idx >> 9, kt = rem % NKT, j = rem / NKT;
  int k = kt*32 + ((l >> 4) << 3) + e;
  int c = j*16 + (l & 15);
  float v = 0.f;
  if (k < 204) {
    if (c < 384)      v = (k < 12) ? Wih[c*MM + k] : Whh[(size_t)c*DD + (k-12)];
    else if (c < 576) v = (k < 12) ? Wih[c*MM + k] : 0.f;
    else              v = (k < 12) ? 0.f : Whh[(size_t)(c-192)*DD + (k-12)];
  }
  unsigned short hi = f2bf(v);
  Bhi[idx] = hi;
  Blo[idx] = f2bf(v - bf2f(hi));
}

// ---------------------------------------------------------------- k_pack_link
// W1^T [32(K) x 512(N)] into B-fragment layout, hi/lo.
__global__ void k_pack_link(const float* __restrict__ w1,
                            unsigned short* __restrict__ BLh,
                            unsigned short* __restrict__ BLl)
{
  int idx = blockIdx.x * 256 + threadIdx.x;
  if (idx >= 32*512) return;
  int e = idx & 7, l = (idx >> 3) & 63, nt = idx >> 9;
  int k = ((l >> 4) << 3) + e;
  int c = nt*16 + (l & 15);
  float v = (k < 12) ? w1[c*EE + k] : 0.f;
  unsigned short h = f2bf(v);
  BLh[idx] = h;
  BLl[idx] = f2bf(v - bf2f(h));
}

// ---------------------------------------------------------------- k_link
// Batched link MLP over all edges via MFMA with fused relu->w2->sigmoid.
// A = edge state [EPW x 32] (L0: masked cat(pos_i,pos_j); L1: m), hi/lo in LDS.
// Per wave: 64 edges (4 m-tiles); loop 32 n-tiles of W1^T; per (mt,nt):
// 3 MFMA (hi/lo split) -> s[mt][q] += w2[col]*relu(acc+b1[col]); butterfly
// reduce over 16 cols -> adj = sigmoid(s + b2).
template<int LAYER>
__global__ __launch_bounds__(128, 4)
void k_link(const float* __restrict__ pos, const int* __restrict__ attmat,
            const float* __restrict__ wsm,
            const unsigned short* __restrict__ BLh, const unsigned short* __restrict__ BLl,
            const float* __restrict__ link_b1, const float* __restrict__ link_w2,
            const float* __restrict__ link_b2,
            float* __restrict__ wsadj)
{
  __shared__ unsigned short sAh[EPW][APL];
  __shared__ unsigned short sAl[EPW][APL];
  const int tid = threadIdx.x;
  const int ge0 = blockIdx.x * EPW;

  {  // build A row for edge ge0+tid
    int ge = ge0 + tid;
    float ev[12];
    if (LAYER == 0) {
      int bt = ge / 36, e36 = ge % 36;
      int i_ = e36 / 6, j_ = e36 % 6;
      bool msk = (attmat[bt*36 + e36] == 1) && (i_ != j_);
      const float* pi = pos + (size_t)bt*36 + i_*6;
      const float* pj = pos + (size_t)bt*36 + j_*6;
      #pragma unroll
      for (int c = 0; c < 6; ++c) {
        ev[c]   = msk ? pi[c] : 0.f;
        ev[6+c] = msk ? pj[c] : 0.f;
      }
    } else {
      const float4* m4 = (const float4*)(wsm + (size_t)ge*12);
      float4 a = m4[0], b = m4[1], c4 = m4[2];
      ev[0]=a.x; ev[1]=a.y; ev[2]=a.z; ev[3]=a.w;
      ev[4]=b.x; ev[5]=b.y; ev[6]=b.z; ev[7]=b.w;
      ev[8]=c4.x; ev[9]=c4.y; ev[10]=c4.z; ev[11]=c4.w;
    }
    unsigned int* dh = (unsigned int*)&sAh[tid][0];
    unsigned int* dl = (unsigned int*)&sAl[tid][0];
    #pragma unroll
    for (int p = 0; p < 16; ++p) {
      float a0 = (2*p   < 12) ? ev[2*p]   : 0.f;
      float a1 = (2*p+1 < 12) ? ev[2*p+1] : 0.f;
      unsigned short h0 = f2bf(a0), h1 = f2bf(a1);
      dh[p] = (unsigned int)h0 | ((unsigned int)h1 << 16);
      dl[p] = (unsigned int)f2bf(a0 - bf2f(h0)) | ((unsigned int)f2bf(a1 - bf2f(h1)) << 16);
    }
  }
  __syncthreads();

  const int lane = tid & 63, wave = tid >> 6;
  const int col = lane & 15, quad = lane >> 4;

  bf16x8 amh[4], aml[4];   // A frags: row = wave*64 + mt*16 + col, k = quad*8..+7
  #pragma unroll
  for (int mt = 0; mt < 4; ++mt) {
    const char* bh_ = (const char*)&sAh[wave*64 + mt*16 + col][0] + quad*16;
    const char* bl_ = (const char*)&sAl[wave*64 + mt*16 + col][0] + quad*16;
    amh[mt] = *(const bf16x8*)bh_;
    aml[mt] = *(const bf16x8*)bl_;
  }

  float s[4][4];
  #pragma unroll
  for (int mt = 0; mt < 4; ++mt)
    #pragma unroll
    for (int q = 0; q < 4; ++q) s[mt][q] = 0.f;

  for (int nt = 0; nt < 32; ++nt) {
    bf16x8 bh = *(const bf16x8*)(BLh + nt*512 + lane*8);
    bf16x8 bl = *(const bf16x8*)(BLl + nt*512 + lane*8);
    float b1v = link_b1[nt*16 + col];
    float w2v = link_w2[nt*16 + col];
    #pragma unroll
    for (int mt = 0; mt < 4; ++mt) {
      f32x4 acc = (f32x4)0.f;
      acc = __builtin_amdgcn_mfma_f32_16x16x32_bf16(amh[mt], bl, acc, 0, 0, 0);
      acc = __builtin_amdgcn_mfma_f32_16x16x32_bf16(aml[mt], bh, acc, 0, 0, 0);
      acc = __builtin_amdgcn_mfma_f32_16x16x32_bf16(amh[mt], bh, acc, 0, 0, 0);
      #pragma unroll
      for (int q = 0; q < 4; ++q)
        s[mt][q] += w2v * fmaxf(acc[q] + b1v, 0.f);
    }
  }
  // reduce across the 16 cols (lane bits 0..3)
  #pragma unroll
  for (int mt = 0; mt < 4; ++mt)
    #pragma unroll
    for (int q = 0; q < 4; ++q) {
      float v = s[mt][q];
      v += __shfl_xor(v, 1); v += __shfl_xor(v, 2);
      v += __shfl_xor(v, 4); v += __shfl_xor(v, 8);
      s[mt][q] = v;
    }
  if (col == 0) {
    float b2 = link_b2[0];
    #pragma unroll
    for (int mt = 0; mt < 4; ++mt)
      #pragma unroll
      for (int q = 0; q < 4; ++q)
        wsadj[ge0 + wave*64 + mt*16 + quad*4 + q] = sigmoidf_(s[mt][q] + b2);
  }
}

// ---------------------------------------------------------------- k_edge
// Light per-(b,t) kernel: messages + msum, using precomputed adj.
// me term uses ORIGINAL edge features e in BOTH layers.
#define EBLK 256
template<int LAYER>
__global__ __launch_bounds__(EBLK, 4)
void k_edge(const float* __restrict__ node_resnet,
            const float* __restrict__ pos, const int* __restrict__ attmat,
            const float* __restrict__ msg_Wh, const float* __restrict__ msg_We,
            const float* __restrict__ msg_b,  const float* __restrict__ wsadj,
            float* __restrict__ wsh, float* __restrict__ wsm, float* __restrict__ wsum)
{
  __shared__ __align__(16) float sh_h[NN][DD+4];
  __shared__ __align__(16) float sh_e[36][EE];
  __shared__ __align__(16) float sh_m[36][MM];
  __shared__ __align__(16) float sh_mh[NN][MM];
  __shared__ float sh_adj[36];
  const int tid = threadIdx.x;
  const int bt = blockIdx.x;

  if (LAYER == 0) {
    for (int i = tid; i < DD*NN; i += EBLK) {
      int d = i / NN, n = i % NN;
      sh_h[n][d] = node_resnet[(size_t)bt*DD*NN + i];
    }
  } else {
    for (int i = tid; i < NN*DD; i += EBLK)
      sh_h[i/DD][i%DD] = wsh[(size_t)bt*NN*DD + i];
  }
  for (int idx = tid; idx < 36*EE; idx += EBLK) {
    int e = idx / EE, c = idx % EE;
    int i_ = e / NN, j_ = e % NN;
    int srcn = (c < 6) ? i_ : j_;
    int cc   = (c < 6) ? c  : c - 6;
    float v = pos[bt*36 + srcn*6 + cc];
    bool msk = (attmat[bt*36 + e] == 1) && (i_ != j_);
    sh_e[e][c] = msk ? v : 0.f;
  }
  if (tid < 36) sh_adj[tid] = wsadj[bt*36 + tid];
  __syncthreads();

  if (LAYER == 0) {   // persist transposed h
    for (int i = tid; i < NN*DD; i += EBLK)
      wsh[(size_t)bt*NN*DD + i] = sh_h[i/DD][i%DD];
  }
  // mh[n][o] = msg_b[o] + Wh[o,:] . h[n,:]
  if (tid < NN*MM) {
    int n = tid / MM, o = tid % MM;
    const float4* wrow = (const float4*)(msg_Wh + (size_t)o*DD);
    const float4* hrow = (const float4*)&sh_h[n][0];
    float acc = msg_b[o];
    #pragma unroll 8
    for (int d4 = 0; d4 < DD/4; ++d4) acc += dot4(wrow[d4], hrow[d4]);
    sh_mh[n][o] = acc;
  }
  __syncthreads();

  for (int idx = tid; idx < 36*MM; idx += EBLK) {
    int e = idx / MM, o = idx % MM;
    int j_ = e % NN;
    const float4* we = (const float4*)(msg_We + o*EE);
    const float4* ev = (const float4*)&sh_e[e][0];
    float me = dot4(we[0],ev[0]) + dot4(we[1],ev[1]) + dot4(we[2],ev[2]);
    float mv = sh_adj[e] * fmaxf(sh_mh[j_][o] + me, 0.f);
    sh_m[e][o] = mv;
    if (LAYER == 0) wsm[(size_t)bt*36*MM + idx] = mv;   // only L1-link consumes it
  }
  __syncthreads();
  if (tid < NN*MM) {
    int i_ = tid / MM, o = tid % MM;
    float s = 0.f;
    #pragma unroll
    for (int j = 0; j < NN; ++j) s += sh_m[i_*NN + j][o];
    wsum[(size_t)bt*NN*MM + tid] = s;
  }
}

// ---------------------------------------------------------------- k_gru_mfma
#define GMT 32
__global__ __launch_bounds__(256, 2)
void k_gru_mfma(const unsigned short* __restrict__ Bhi,
                const unsigned short* __restrict__ Blo,
                const float* __restrict__ bias768,
                const float* __restrict__ wsum,
                float* __restrict__ wsh)
{
  __shared__ unsigned int sAhi[GMT][APITCH/2];
  __shared__ unsigned int sAlo[GMT][APITCH/2];
  const int tid = threadIdx.x;
  const int row0 = blockIdx.x * GMT;

  for (int i = tid; i < GMT*(KPAD/2); i += 256) {
    int r = i / (KPAD/2), kp = i % (KPAD/2);
    int k0 = kp*2, k1 = k0+1;
    int grow = row0 + r;
    float a0 = (k0 < 12) ? wsum[(size_t)grow*MM + k0]
             : (k0 < 204 ? wsh[(size_t)grow*DD + (k0-12)] : 0.f);
    float a1 = (k1 < 12) ? wsum[(size_t)grow*MM + k1]
             : (k1 < 204 ? wsh[(size_t)grow*DD + (k1-12)] : 0.f);
    unsigned short h0 = f2bf(a0), h1 = f2bf(a1);
    unsigned short l0 = f2bf(a0 - bf2f(h0)), l1 = f2bf(a1 - bf2f(h1));
    sAhi[r][kp] = (unsigned int)h0 | ((unsigned int)h1 << 16);
    sAlo[r][kp] = (unsigned int)l0 | ((unsigned int)l1 << 16);
  }
  __syncthreads();

  const int lane = tid & 63;
  const int wid  = tid >> 6;
  const int col  = lane & 15;
  const int quad = lane >> 4;

  f32x4 acc[4][3][2];
  #pragma unroll
  for (int g = 0; g < 4; ++g)
    #pragma unroll
    for (int i = 0; i < 3; ++i)
      #pragma unroll
      for (int rt = 0; rt < 2; ++rt) acc[g][i][rt] = (f32x4)0.f;

  const char* ahb = (const char*)&sAhi[0][0] + col*(APITCH*2) + quad*16;
  const char* alb = (const char*)&sAlo[0][0] + col*(APITCH*2) + quad*16;

  for (int kt = 0; kt < NKT; ++kt) {
    bf16x8 ah0 = *(const bf16x8*)(ahb + kt*64);
    bf16x8 ah1 = *(const bf16x8*)(ahb + 16*(APITCH*2) + kt*64);
    bf16x8 al0 = *(const bf16x8*)(alb + kt*64);
    bf16x8 al1 = *(const bf16x8*)(alb + 16*(APITCH*2) + kt*64);
    #pragma unroll
    for (int g = 0; g < 4; ++g) {
      #pragma unroll
      for (int i = 0; i < 3; ++i) {
        const int j = g*12 + wid*3 + i;
        const size_t off = ((size_t)(j*NKT + kt) << 9) + lane*8;
        bf16x8 bh = *(const bf16x8*)(Bhi + off);
        bf16x8 bl = *(const bf16x8*)(Blo + off);
        acc[g][i][0] = __builtin_amdgcn_mfma_f32_16x16x32_bf16(ah0, bl, acc[g][i][0], 0, 0, 0);
        acc[g][i][0] = __builtin_amdgcn_mfma_f32_16x16x32_bf16(al0, bh, acc[g][i][0], 0, 0, 0);
        acc[g][i][0] = __builtin_amdgcn_mfma_f32_16x16x32_bf16(ah0, bh, acc[g][i][0], 0, 0, 0);
        acc[g][i][1] = __builtin_amdgcn_mfma_f32_16x16x32_bf16(ah1, bl, acc[g][i][1], 0, 0, 0);
        acc[g][i][1] = __builtin_amdgcn_mfma_f32_16x16x32_bf16(al1, bh, acc[g][i][1], 0, 0, 0);
        acc[g][i][1] = __builtin_amdgcn_mfma_f32_16x16x32_bf16(ah1, bh, acc[g][i][1], 0, 0, 0);
      }
    }
  }

  #pragma unroll
  for (int i = 0; i < 3; ++i) {
    const int dt = wid*3 + i;
    const int d  = dt*16 + col;
    const float bR = bias768[d], bZ = bias768[192 + d];
    const float bI = bias768[384 + d], bH = bias768[576 + d];
    #pragma unroll
    for (int rt = 0; rt < 2; ++rt) {
      #pragma unroll
      for (int q = 0; q < 4; ++q) {
        const int grow = row0 + rt*16 + quad*4 + q;
        float r_ = sigmoidf_(acc[0][i][rt][q] + bR);
        float z_ = sigmoidf_(acc[1][i][rt][q] + bZ);
        float n_ = tanhf(acc[2][i][rt][q] + bI + r_*(acc[3][i][rt][q] + bH));
        float hold = wsh[(size_t)grow*DD + d];
        wsh[(size_t)grow*DD + d] = (1.f - z_)*n_ + z_*hold;
      }
    }
  }
}

// ---------------------------------------------------------------- k_conv
#define CBLK 256
__global__ __launch_bounds__(CBLK, 4)
void k_conv(const float* __restrict__ wsh,
            const float* __restrict__ conv1_w, const float* __restrict__ conv1_b,
            const float* __restrict__ conv2_w, const float* __restrict__ conv2_b,
            float* __restrict__ out)
{
  __shared__ float sh_h[TT*NN][DD+4];
  __shared__ float red[CBLK/64][OO];
  const int tid = threadIdx.x;
  const int b = blockIdx.x;
  for (int i = tid; i < TT*NN*DD; i += CBLK)
    sh_h[i/DD][i%DD] = wsh[(size_t)b*TT*NN*DD + i];
  __syncthreads();
  float acc[OO];
  #pragma unroll
  for (int o = 0; o < OO; ++o) acc[o] = 0.f;
  #pragma unroll
  for (int o = 0; o < OO; ++o) {
    const float* wo = conv1_w + (size_t)o*DD*TT*NN;
    for (int u = tid; u < DD*TT*NN; u += CBLK) {
      int n = u % NN; int t = (u / NN) % TT; int d = u / (NN*TT);
      acc[o] += wo[u] * sh_h[t*NN + n][d];
    }
  }
  #pragma unroll
  for (int o = 0; o < OO; ++o) {
    float v = acc[o];
    v += __shfl_xor(v, 1);  v += __shfl_xor(v, 2);  v += __shfl_xor(v, 4);
    v += __shfl_xor(v, 8);  v += __shfl_xor(v, 16); v += __shfl_xor(v, 32);
    acc[o] = v;
  }
  if ((tid & 63) == 0) {
    #pragma unroll
    for (int o = 0; o < OO; ++o) red[tid >> 6][o] = acc[o];
  }
  __syncthreads();
  if (tid == 0) {
    float y[OO];
    #pragma unroll
    for (int o = 0; o < OO; ++o) {
      float s = conv1_b[o];
      #pragma unroll
      for (int w = 0; w < CBLK/64; ++w) s += red[w][o];
      y[o] = fmaxf(s, 0.f);
    }
    #pragma unroll
    for (int q = 0; q < OO; ++q) {
      float s = conv2_b[q];
      #pragma unroll
      for (int o = 0; o < OO; ++o) s += conv2_w[q*OO + o] * y[o];
      out[b*OO + q] = s;
    }
  }
}

// ---------------------------------------------------------------- launch
extern "C" void kernel_launch(void* const* d_in, const int* in_sizes, int n_in,
                              void* d_out, int out_size, void* d_ws, size_t ws_size,
                              hipStream_t stream) {
  const float* node_resnet = (const float*)d_in[0];
  const float* pos      = (const float*)d_in[1];
  const int*   attmat   = (const int*)  d_in[2];
  const float* link_w1  = (const float*)d_in[3];
  const float* link_b1  = (const float*)d_in[4];
  const float* link_w2  = (const float*)d_in[5];
  const float* link_b2  = (const float*)d_in[6];
  const float* msg_Wh   = (const float*)d_in[7];
  const float* msg_We   = (const float*)d_in[8];
  const float* msg_b    = (const float*)d_in[9];
  const float* gru_Wih  = (const float*)d_in[10];
  const float* gru_Whh  = (const float*)d_in[11];
  const float* gru_bih  = (const float*)d_in[12];
  const float* gru_bhh  = (const float*)d_in[13];
  const float* conv1_w  = (const float*)d_in[14];
  const float* conv1_b  = (const float*)d_in[15];
  const float* conv2_w  = (const float*)d_in[16];
  const float* conv2_b  = (const float*)d_in[17];
  float* out = (float*)d_out;

  // ws layout (floats): wsh | wsm | wsum | bias768 | Bhi | Blo | BLh | BLl | wsadj
  float* wsh  = (float*)d_ws;
  float* wsm  = wsh  + (size_t)NROW*DD;
  float* wsum = wsm  + (size_t)BT_TOTAL*36*MM;
  float* bias = wsum + (size_t)NROW*MM;
  unsigned short* Bhi = (unsigned short*)(bias + GOUT);
  unsigned short* Blo = Bhi + (size_t)NJT*NKT*512;
  unsigned short* BLh = Blo + (size_t)NJT*NKT*512;
  unsigned short* BLl = BLh + (size_t)32*512;
  float* wsadj = (float*)(BLl + (size_t)32*512);

  k_pack<<<(NJT*NKT*512 + 255)/256, 256, 0, stream>>>(gru_Wih, gru_Whh,
      gru_bih, gru_bhh, Bhi, Blo, bias);
  k_pack_link<<<(32*512 + 255)/256, 256, 0, stream>>>(link_w1, BLh, BLl);

  k_link<0><<<NEDGE/EPW, 128, 0, stream>>>(pos, attmat, wsm, BLh, BLl,
      link_b1, link_w2, link_b2, wsadj);
  k_edge<0><<<BT_TOTAL, EBLK, 0, stream>>>(node_resnet, pos, attmat,
      msg_Wh, msg_We, msg_b, wsadj, wsh, wsm, wsum);
  k_gru_mfma<<<NROW/GMT, 256, 0, stream>>>(Bhi, Blo, bias, wsum, wsh);

  k_link<1><<<NEDGE/EPW, 128, 0, stream>>>(pos, attmat, wsm, BLh, BLl,
      link_b1, link_w2, link_b2, wsadj);
  k_edge<1><<<BT_TOTAL, EBLK, 0, stream>>>(node_resnet, pos, attmat,
      msg_Wh, msg_We, msg_b, wsadj, wsh, wsm, wsum);
  k_gru_mfma<<<NROW/GMT, 256, 0, stream>>>(Bhi, Blo, bias, wsum, wsh);

  k_conv<<<NB, CBLK, 0, stream>>>(wsh, conv1_w, conv1_b, conv2_w, conv2_b, out);
}

// Round 6
// 278.435 us; speedup vs baseline: 11.9535x; 1.2525x over previous
//
#include <hip/hip_runtime.h>
#include <math.h>

// Sizes (fixed by the reference)
#define NB 1024
#define TT 5
#define NN 6
#define DD 192
#define EE 12
#define MM 12
#define LL 512
#define OO 6
#define BT_TOTAL (NB*TT)      // 5120
#define NROW (BT_TOTAL*NN)    // 30720 GRU rows
#define NEDGE (BT_TOTAL*36)   // 184320 edges
#define GATE (3*DD)           // 576
#define GOUT 768              // GRU GEMM N: [r|z|inn|hn]
#define KPAD 224              // GRU K: 12 + 192 + 20 pad
#define NKT (KPAD/32)         // 7 k-tiles
#define NJT (GOUT/16)         // 48 n-tiles
#define APITCH 232            // GRU A LDS pitch (fp16 elems; 464 B)

#define EPW 128               // edges per WG in k_link
#define APL 40                // k_link A LDS pitch in fp16 (80 B)

typedef __attribute__((ext_vector_type(8))) _Float16 f16x8;
typedef __attribute__((ext_vector_type(4))) float f32x4;

__device__ __forceinline__ float sigmoidf_(float x) { return 1.f / (1.f + __expf(-x)); }
__device__ __forceinline__ float dot4(float4 a, float4 b) {
  return a.x*b.x + a.y*b.y + a.z*b.z + a.w*b.w;
}
__device__ __forceinline__ unsigned short f2h(float f) {
  _Float16 h = (_Float16)f;            // RTN-even
  unsigned short s; __builtin_memcpy(&s, &h, 2); return s;
}
__device__ __forceinline__ unsigned int pack2h(float a, float b) {
  return (unsigned int)f2h(a) | ((unsigned int)f2h(b) << 16);
}

// ---------------------------------------------------------------- k_pack (GRU W, fp16)
// W' [KPAD x GOUT] -> B-fragment layout (single fp16). Also fused bias768.
__global__ void k_pack(const float* __restrict__ Wih, const float* __restrict__ Whh,
                       const float* __restrict__ bih, const float* __restrict__ bhh,
                       unsigned short* __restrict__ Bh, float* __restrict__ bias768)
{
  int idx = blockIdx.x * 256 + threadIdx.x;
  if (idx < GOUT) {
    int c = idx; float b;
    if (c < 384)      b = bih[c] + bhh[c];
    else if (c < 576) b = bih[c];
    else              b = bhh[c - 192];
    bias768[c] = b;
  }
  if (idx >= NJT*NKT*512) return;
  int e = idx & 7, l = (idx >> 3) & 63;
  int rem = idx >> 9, kt = rem % NKT, j = rem / NKT;
  int k = kt*32 + ((l >> 4) << 3) + e;
  int c = j*16 + (l & 15);
  float v = 0.f;
  if (k < 204) {
    if (c < 384)      v = (k < 12) ? Wih[c*MM + k] : Whh[(size_t)c*DD + (k-12)];
    else if (c < 576) v = (k < 12) ? Wih[c*MM + k] : 0.f;
    else              v = (k < 12) ? 0.f : Whh[(size_t)(c-192)*DD + (k-12)];
  }
  Bh[idx] = f2h(v);
}

// ---------------------------------------------------------------- k_pack_link (fp16)
__global__ void k_pack_link(const float* __restrict__ w1,
                            unsigned short* __restrict__ BLh)
{
  int idx = blockIdx.x * 256 + threadIdx.x;
  if (idx >= 32*512) return;
  int e = idx & 7, l = (idx >> 3) & 63, nt = idx >> 9;
  int k = ((l >> 4) << 3) + e;
  int c = nt*16 + (l & 15);
  float v = (k < 12) ? w1[c*EE + k] : 0.f;
  BLh[idx] = f2h(v);
}

// ---------------------------------------------------------------- k_link
// Batched link MLP (fp16 MFMA) with fused relu->w2->sigmoid.
template<int LAYER>
__global__ __launch_bounds__(128, 4)
void k_link(const float* __restrict__ pos, const int* __restrict__ attmat,
            const float* __restrict__ wsm,
            const unsigned short* __restrict__ BLh,
            const float* __restrict__ link_b1, const float* __restrict__ link_w2,
            const float* __restrict__ link_b2,
            float* __restrict__ wsadj)
{
  __shared__ unsigned short sAh[EPW][APL];
  const int tid = threadIdx.x;
  const int ge0 = blockIdx.x * EPW;

  {  // build A row for edge ge0+tid
    int ge = ge0 + tid;
    float ev[12];
    if (LAYER == 0) {
      int bt = ge / 36, e36 = ge % 36;
      int i_ = e36 / 6, j_ = e36 % 6;
      bool msk = (attmat[bt*36 + e36] == 1) && (i_ != j_);
      const float* pi = pos + (size_t)bt*36 + i_*6;
      const float* pj = pos + (size_t)bt*36 + j_*6;
      #pragma unroll
      for (int c = 0; c < 6; ++c) {
        ev[c]   = msk ? pi[c] : 0.f;
        ev[6+c] = msk ? pj[c] : 0.f;
      }
    } else {
      const float4* m4 = (const float4*)(wsm + (size_t)ge*12);
      float4 a = m4[0], b = m4[1], c4 = m4[2];
      ev[0]=a.x; ev[1]=a.y; ev[2]=a.z; ev[3]=a.w;
      ev[4]=b.x; ev[5]=b.y; ev[6]=b.z; ev[7]=b.w;
      ev[8]=c4.x; ev[9]=c4.y; ev[10]=c4.z; ev[11]=c4.w;
    }
    unsigned int* dh = (unsigned int*)&sAh[tid][0];
    #pragma unroll
    for (int p = 0; p < 16; ++p) {
      float a0 = (2*p   < 12) ? ev[2*p]   : 0.f;
      float a1 = (2*p+1 < 12) ? ev[2*p+1] : 0.f;
      dh[p] = pack2h(a0, a1);
    }
  }
  __syncthreads();

  const int lane = tid & 63, wave = tid >> 6;
  const int col = lane & 15, quad = lane >> 4;

  f16x8 amh[4];   // A frags: row = wave*64 + mt*16 + col, k = quad*8..+7
  #pragma unroll
  for (int mt = 0; mt < 4; ++mt)
    amh[mt] = *(const f16x8*)((const char*)&sAh[wave*64 + mt*16 + col][0] + quad*16);

  float s[4][4];
  #pragma unroll
  for (int mt = 0; mt < 4; ++mt)
    #pragma unroll
    for (int q = 0; q < 4; ++q) s[mt][q] = 0.f;

  for (int nt = 0; nt < 32; ++nt) {
    f16x8 bh = *(const f16x8*)(BLh + nt*512 + lane*8);
    float b1v = link_b1[nt*16 + col];
    float w2v = link_w2[nt*16 + col];
    #pragma unroll
    for (int mt = 0; mt < 4; ++mt) {
      f32x4 acc = (f32x4)0.f;
      acc = __builtin_amdgcn_mfma_f32_16x16x32_f16(amh[mt], bh, acc, 0, 0, 0);
      #pragma unroll
      for (int q = 0; q < 4; ++q)
        s[mt][q] += w2v * fmaxf(acc[q] + b1v, 0.f);
    }
  }
  #pragma unroll
  for (int mt = 0; mt < 4; ++mt)
    #pragma unroll
    for (int q = 0; q < 4; ++q) {
      float v = s[mt][q];
      v += __shfl_xor(v, 1); v += __shfl_xor(v, 2);
      v += __shfl_xor(v, 4); v += __shfl_xor(v, 8);
      s[mt][q] = v;
    }
  if (col == 0) {
    float b2 = link_b2[0];
    #pragma unroll
    for (int mt = 0; mt < 4; ++mt)
      #pragma unroll
      for (int q = 0; q < 4; ++q)
        wsadj[ge0 + wave*64 + mt*16 + quad*4 + q] = sigmoidf_(s[mt][q] + b2);
  }
}

// ---------------------------------------------------------------- k_edge (unchanged)
#define EBLK 256
template<int LAYER>
__global__ __launch_bounds__(EBLK, 4)
void k_edge(const float* __restrict__ node_resnet,
            const float* __restrict__ pos, const int* __restrict__ attmat,
            const float* __restrict__ msg_Wh, const float* __restrict__ msg_We,
            const float* __restrict__ msg_b,  const float* __restrict__ wsadj,
            float* __restrict__ wsh, float* __restrict__ wsm, float* __restrict__ wsum)
{
  __shared__ __align__(16) float sh_h[NN][DD+4];
  __shared__ __align__(16) float sh_e[36][EE];
  __shared__ __align__(16) float sh_m[36][MM];
  __shared__ __align__(16) float sh_mh[NN][MM];
  __shared__ float sh_adj[36];
  const int tid = threadIdx.x;
  const int bt = blockIdx.x;

  if (LAYER == 0) {
    for (int i = tid; i < DD*NN; i += EBLK) {
      int d = i / NN, n = i % NN;
      sh_h[n][d] = node_resnet[(size_t)bt*DD*NN + i];
    }
  } else {
    for (int i = tid; i < NN*DD; i += EBLK)
      sh_h[i/DD][i%DD] = wsh[(size_t)bt*NN*DD + i];
  }
  for (int idx = tid; idx < 36*EE; idx += EBLK) {
    int e = idx / EE, c = idx % EE;
    int i_ = e / NN, j_ = e % NN;
    int srcn = (c < 6) ? i_ : j_;
    int cc   = (c < 6) ? c  : c - 6;
    float v = pos[bt*36 + srcn*6 + cc];
    bool msk = (attmat[bt*36 + e] == 1) && (i_ != j_);
    sh_e[e][c] = msk ? v : 0.f;
  }
  if (tid < 36) sh_adj[tid] = wsadj[bt*36 + tid];
  __syncthreads();

  if (LAYER == 0) {
    for (int i = tid; i < NN*DD; i += EBLK)
      wsh[(size_t)bt*NN*DD + i] = sh_h[i/DD][i%DD];
  }
  if (tid < NN*MM) {
    int n = tid / MM, o = tid % MM;
    const float4* wrow = (const float4*)(msg_Wh + (size_t)o*DD);
    const float4* hrow = (const float4*)&sh_h[n][0];
    float acc = msg_b[o];
    #pragma unroll 8
    for (int d4 = 0; d4 < DD/4; ++d4) acc += dot4(wrow[d4], hrow[d4]);
    sh_mh[n][o] = acc;
  }
  __syncthreads();

  for (int idx = tid; idx < 36*MM; idx += EBLK) {
    int e = idx / MM, o = idx % MM;
    int j_ = e % NN;
    const float4* we = (const float4*)(msg_We + o*EE);
    const float4* ev = (const float4*)&sh_e[e][0];
    float me = dot4(we[0],ev[0]) + dot4(we[1],ev[1]) + dot4(we[2],ev[2]);
    float mv = sh_adj[e] * fmaxf(sh_mh[j_][o] + me, 0.f);
    sh_m[e][o] = mv;
    if (LAYER == 0) wsm[(size_t)bt*36*MM + idx] = mv;
  }
  __syncthreads();
  if (tid < NN*MM) {
    int i_ = tid / MM, o = tid % MM;
    float s = 0.f;
    #pragma unroll
    for (int j = 0; j < NN; ++j) s += sh_m[i_*NN + j][o];
    wsum[(size_t)bt*NN*MM + tid] = s;
  }
}

// ---------------------------------------------------------------- k_gru_mfma (fp16)
// [32 x 224] x [224 x 768], single fp16 product. Wave w owns d-tiles
// {3w..3w+2} x gates {r,z,inn,hn}; 1 independent MFMA per acc per iter.
#define GMT 32
__global__ __launch_bounds__(256, 3)
void k_gru_mfma(const unsigned short* __restrict__ Bh,
                const float* __restrict__ bias768,
                const float* __restrict__ wsum,
                float* __restrict__ wsh)
{
  __shared__ unsigned int sA[GMT][APITCH/2];   // fp16 pairs, 464 B pitch
  const int tid = threadIdx.x;
  const int row0 = blockIdx.x * GMT;

  for (int i = tid; i < GMT*(KPAD/2); i += 256) {
    int r = i / (KPAD/2), kp = i % (KPAD/2);
    int k0 = kp*2, k1 = k0+1;
    int grow = row0 + r;
    float a0 = (k0 < 12) ? wsum[(size_t)grow*MM + k0]
             : (k0 < 204 ? wsh[(size_t)grow*DD + (k0-12)] : 0.f);
    float a1 = (k1 < 12) ? wsum[(size_t)grow*MM + k1]
             : (k1 < 204 ? wsh[(size_t)grow*DD + (k1-12)] : 0.f);
    sA[r][kp] = pack2h(a0, a1);
  }
  __syncthreads();

  const int lane = tid & 63;
  const int wid  = tid >> 6;
  const int col  = lane & 15;
  const int quad = lane >> 4;

  f32x4 acc[4][3][2];   // [gate][dt local][row-tile]
  #pragma unroll
  for (int g = 0; g < 4; ++g)
    #pragma unroll
    for (int i = 0; i < 3; ++i)
      #pragma unroll
      for (int rt = 0; rt < 2; ++rt) acc[g][i][rt] = (f32x4)0.f;

  const char* ahb = (const char*)&sA[0][0] + col*(APITCH*2) + quad*16;

  for (int kt = 0; kt < NKT; ++kt) {
    f16x8 ah0 = *(const f16x8*)(ahb + kt*64);
    f16x8 ah1 = *(const f16x8*)(ahb + 16*(APITCH*2) + kt*64);
    #pragma unroll
    for (int gp = 0; gp < 2; ++gp) {   // 2 gate-pairs: hoist 6 B loads each
      f16x8 bf[6];
      #pragma unroll
      for (int u = 0; u < 6; ++u) {
        const int g = gp*2 + u/3, i = u%3;
        const int j = g*12 + wid*3 + i;
        bf[u] = *(const f16x8*)(Bh + (((size_t)(j*NKT + kt)) << 9) + lane*8);
      }
      #pragma unroll
      for (int u = 0; u < 6; ++u) {
        const int g = gp*2 + u/3, i = u%3;
        acc[g][i][0] = __builtin_amdgcn_mfma_f32_16x16x32_f16(ah0, bf[u], acc[g][i][0], 0, 0, 0);
        acc[g][i][1] = __builtin_amdgcn_mfma_f32_16x16x32_f16(ah1, bf[u], acc[g][i][1], 0, 0, 0);
      }
    }
  }

  #pragma unroll
  for (int i = 0; i < 3; ++i) {
    const int dt = wid*3 + i;
    const int d  = dt*16 + col;
    const float bR = bias768[d], bZ = bias768[192 + d];
    const float bI = bias768[384 + d], bH = bias768[576 + d];
    #pragma unroll
    for (int rt = 0; rt < 2; ++rt) {
      #pragma unroll
      for (int q = 0; q < 4; ++q) {
        const int grow = row0 + rt*16 + quad*4 + q;
        float r_ = sigmoidf_(acc[0][i][rt][q] + bR);
        float z_ = sigmoidf_(acc[1][i][rt][q] + bZ);
        float n_ = tanhf(acc[2][i][rt][q] + bI + r_*(acc[3][i][rt][q] + bH));
        float hold = wsh[(size_t)grow*DD + d];
        wsh[(size_t)grow*DD + d] = (1.f - z_)*n_ + z_*hold;
      }
    }
  }
}

// ---------------------------------------------------------------- k_conv (unchanged)
#define CBLK 256
__global__ __launch_bounds__(CBLK, 4)
void k_conv(const float* __restrict__ wsh,
            const float* __restrict__ conv1_w, const float* __restrict__ conv1_b,
            const float* __restrict__ conv2_w, const float* __restrict__ conv2_b,
            float* __restrict__ out)
{
  __shared__ float sh_h[TT*NN][DD+4];
  __shared__ float red[CBLK/64][OO];
  const int tid = threadIdx.x;
  const int b = blockIdx.x;
  for (int i = tid; i < TT*NN*DD; i += CBLK)
    sh_h[i/DD][i%DD] = wsh[(size_t)b*TT*NN*DD + i];
  __syncthreads();
  float acc[OO];
  #pragma unroll
  for (int o = 0; o < OO; ++o) acc[o] = 0.f;
  #pragma unroll
  for (int o = 0; o < OO; ++o) {
    const float* wo = conv1_w + (size_t)o*DD*TT*NN;
    for (int u = tid; u < DD*TT*NN; u += CBLK) {
      int n = u % NN; int t = (u / NN) % TT; int d = u / (NN*TT);
      acc[o] += wo[u] * sh_h[t*NN + n][d];
    }
  }
  #pragma unroll
  for (int o = 0; o < OO; ++o) {
    float v = acc[o];
    v += __shfl_xor(v, 1);  v += __shfl_xor(v, 2);  v += __shfl_xor(v, 4);
    v += __shfl_xor(v, 8);  v += __shfl_xor(v, 16); v += __shfl_xor(v, 32);
    acc[o] = v;
  }
  if ((tid & 63) == 0) {
    #pragma unroll
    for (int o = 0; o < OO; ++o) red[tid >> 6][o] = acc[o];
  }
  __syncthreads();
  if (tid == 0) {
    float y[OO];
    #pragma unroll
    for (int o = 0; o < OO; ++o) {
      float s = conv1_b[o];
      #pragma unroll
      for (int w = 0; w < CBLK/64; ++w) s += red[w][o];
      y[o] = fmaxf(s, 0.f);
    }
    #pragma unroll
    for (int q = 0; q < OO; ++q) {
      float s = conv2_b[q];
      #pragma unroll
      for (int o = 0; o < OO; ++o) s += conv2_w[q*OO + o] * y[o];
      out[b*OO + q] = s;
    }
  }
}

// ---------------------------------------------------------------- launch
extern "C" void kernel_launch(void* const* d_in, const int* in_sizes, int n_in,
                              void* d_out, int out_size, void* d_ws, size_t ws_size,
                              hipStream_t stream) {
  const float* node_resnet = (const float*)d_in[0];
  const float* pos      = (const float*)d_in[1];
  const int*   attmat   = (const int*)  d_in[2];
  const float* link_w1  = (const float*)d_in[3];
  const float* link_b1  = (const float*)d_in[4];
  const float* link_w2  = (const float*)d_in[5];
  const float* link_b2  = (const float*)d_in[6];
  const float* msg_Wh   = (const float*)d_in[7];
  const float* msg_We   = (const float*)d_in[8];
  const float* msg_b    = (const float*)d_in[9];
  const float* gru_Wih  = (const float*)d_in[10];
  const float* gru_Whh  = (const float*)d_in[11];
  const float* gru_bih  = (const float*)d_in[12];
  const float* gru_bhh  = (const float*)d_in[13];
  const float* conv1_w  = (const float*)d_in[14];
  const float* conv1_b  = (const float*)d_in[15];
  const float* conv2_w  = (const float*)d_in[16];
  const float* conv2_b  = (const float*)d_in[17];
  float* out = (float*)d_out;

  // ws layout (floats): wsh | wsm | wsum | bias768 | Bh(fp16) | BLh(fp16) | wsadj
  float* wsh  = (float*)d_ws;
  float* wsm  = wsh  + (size_t)NROW*DD;
  float* wsum = wsm  + (size_t)BT_TOTAL*36*MM;
  float* bias = wsum + (size_t)NROW*MM;
  unsigned short* Bh  = (unsigned short*)(bias + GOUT);
  unsigned short* BLh = Bh + (size_t)NJT*NKT*512;
  float* wsadj = (float*)(BLh + (size_t)32*512);

  k_pack<<<(NJT*NKT*512 + 255)/256, 256, 0, stream>>>(gru_Wih, gru_Whh,
      gru_bih, gru_bhh, Bh, bias);
  k_pack_link<<<(32*512 + 255)/256, 256, 0, stream>>>(link_w1, BLh);

  k_link<0><<<NEDGE/EPW, 128, 0, stream>>>(pos, attmat, wsm, BLh,
      link_b1, link_w2, link_b2, wsadj);
  k_edge<0><<<BT_TOTAL, EBLK, 0, stream>>>(node_resnet, pos, attmat,
      msg_Wh, msg_We, msg_b, wsadj, wsh, wsm, wsum);
  k_gru_mfma<<<NROW/GMT, 256, 0, stream>>>(Bh, bias, wsum, wsh);

  k_link<1><<<NEDGE/EPW, 128, 0, stream>>>(pos, attmat, wsm, BLh,
      link_b1, link_w2, link_b2, wsadj);
  k_edge<1><<<BT_TOTAL, EBLK, 0, stream>>>(node_resnet, pos, attmat,
      msg_Wh, msg_We, msg_b, wsadj, wsh, wsm, wsum);
  k_gru_mfma<<<NROW/GMT, 256, 0, stream>>>(Bh, bias, wsum, wsh);

  k_conv<<<NB, CBLK, 0, stream>>>(wsh, conv1_w, conv1_b, conv2_w, conv2_b, out);
}